// Round 1
// baseline (815.835 us; speedup 1.0000x reference)
//
#include <hip/hip_runtime.h>

#define NMN 100000
#define NPV 20000
#define DMF 128
#define DPF 64
#define NE  500000
#define HID 128
#define LAT 32
#define NACT (2*NPV)                  // 40000 edge-active nodes
#define OUT_PROV (NMN*DMF)            // 12,800,000
#define OUT_LOG  (OUT_PROV + NPV*DPF) // 14,080,000

__device__ __forceinline__ void fma4(float4& a, float s, float4 w) {
  a.x += s*w.x; a.y += s*w.y; a.z += s*w.z; a.w += s*w.w;
}
__device__ __forceinline__ float4 add4(float4 a, float4 b) {
  return make_float4(a.x+b.x, a.y+b.y, a.z+b.z, a.w+b.w);
}

// ---------------- degree / norm ----------------
__global__ __launch_bounds__(256) void k_deg_init(int* deg) {
  int i = blockIdx.x*256 + threadIdx.x;
  if (i < NACT) deg[i] = 1;           // self-loop
}

__global__ __launch_bounds__(256) void k_deg_count(const int* __restrict__ pidx,
                                                   const int* __restrict__ midx,
                                                   int* __restrict__ deg) {
  int e = blockIdx.x*256 + threadIdx.x;
  if (e >= NE) return;
  atomicAdd(&deg[pidx[e]], 1);                 // dst = provider_idx (member node)
  int m = midx[e];
  if (m < NPV) atomicAdd(&deg[NPV + m], 1);    // dst = m+NM in-bounds only if m<NP
}

__global__ __launch_bounds__(256) void k_dinv(float* buf) {
  int i = blockIdx.x*256 + threadIdx.x;
  if (i < NACT) {
    int d = ((const int*)buf)[i];
    buf[i] = rsqrtf((float)d);
  }
}

// ---------------- GEMM: xw1 = x_active @ W1 (K=128, 128 cols) ----------------
__global__ __launch_bounds__(256) void k_xw1(const float* __restrict__ xm,
                                             const float* __restrict__ xp,
                                             const float* __restrict__ W1,
                                             float* __restrict__ xw1) {
  __shared__ float Wl[DMF*HID];   // 64KB
  __shared__ float rows[32*DMF];  // 16KB
  int tid = threadIdx.x;
  for (int i = tid; i < DMF*HID/4; i += 256)
    ((float4*)Wl)[i] = ((const float4*)W1)[i];
  int rbase = blockIdx.x * 32;
  for (int i = tid; i < 32*DMF/4; i += 256) {
    int r = i >> 5, q = i & 31;
    int a = rbase + r;
    float4 v;
    if (a < NPV) v = ((const float4*)(xm + (size_t)a*DMF))[q];
    else {
      int p = a - NPV;   // provider row: 64 real cols, pad zeros
      v = (q < DPF/4) ? ((const float4*)(xp + (size_t)p*DPF))[q] : make_float4(0,0,0,0);
    }
    ((float4*)rows)[i] = v;
  }
  __syncthreads();
  int w = tid >> 6, l = tid & 63;
  int half = l >> 5, lc = l & 31, c0 = lc*4;
  int r0 = w*8 + half*4;
  float4 a0={0,0,0,0}, a1=a0, a2=a0, a3=a0;
  for (int k = 0; k < DMF; ++k) {
    float4 wv = *(float4*)&Wl[k*HID + c0];
    fma4(a0, rows[(r0+0)*DMF + k], wv);
    fma4(a1, rows[(r0+1)*DMF + k], wv);
    fma4(a2, rows[(r0+2)*DMF + k], wv);
    fma4(a3, rows[(r0+3)*DMF + k], wv);
  }
  int ar = rbase + r0;
  *(float4*)&xw1[(size_t)(ar+0)*HID + c0] = a0;
  *(float4*)&xw1[(size_t)(ar+1)*HID + c0] = a1;
  *(float4*)&xw1[(size_t)(ar+2)*HID + c0] = a2;
  *(float4*)&xw1[(size_t)(ar+3)*HID + c0] = a3;
}

// ---------------- self-loop init: h = dinv^2 * xw1 ----------------
__global__ __launch_bounds__(256) void k_init_h(const float* __restrict__ dinv,
                                                const float* __restrict__ xw1,
                                                float* __restrict__ h) {
  int i = blockIdx.x*256 + threadIdx.x;  // quad idx, exact grid
  int a = i >> 5;
  float di = dinv[a]; float s = di*di;
  float4 v = ((const float4*)xw1)[i];
  ((float4*)h)[i] = make_float4(s*v.x, s*v.y, s*v.z, s*v.w);
}

// ---------------- edge scatter layer 1 (wave = 1 edge, 2 cols/lane) ----------------
__global__ __launch_bounds__(256) void k_scatter1(const int* __restrict__ pidx,
                                                  const int* __restrict__ midx,
                                                  const float* __restrict__ dinv,
                                                  const float* __restrict__ xw1,
                                                  float* __restrict__ h) {
  int t = blockIdx.x*256 + threadIdx.x;
  int e = t >> 6, l = t & 63;          // grid sized exactly: NE*64 threads
  int m = midx[e], p = pidx[e];
  int sa = NPV + (m < NPV-1 ? m : NPV-1);     // clamped gather source (provider side)
  float dp = dinv[p], dsa = dinv[sa];
  // edge: src = m+NM (clamped), dst = p
  float n1 = dsa * dp;
  float2 v = *(const float2*)&xw1[(size_t)sa*HID + 2*l];
  atomicAdd(&h[(size_t)p*HID + 2*l    ], n1*v.x);
  atomicAdd(&h[(size_t)p*HID + 2*l + 1], n1*v.y);
  // edge: src = p, dst = m+NM (dropped if OOB)
  if (m < NPV) {
    int da = NPV + m;
    float n2 = dp * dinv[da];
    float2 u = *(const float2*)&xw1[(size_t)p*HID + 2*l];
    atomicAdd(&h[(size_t)da*HID + 2*l    ], n2*u.x);
    atomicAdd(&h[(size_t)da*HID + 2*l + 1], n2*u.y);
  }
}

// ---------------- finalize h: +b1, relu ----------------
__global__ __launch_bounds__(256) void k_fin_h(const float* __restrict__ b1,
                                               float* __restrict__ h) {
  int i = blockIdx.x*256 + threadIdx.x;
  float4 bv = ((const float4*)b1)[i & 31];
  float4 v = add4(((float4*)h)[i], bv);
  v.x = v.x > 0.f ? v.x : 0.f;
  v.y = v.y > 0.f ? v.y : 0.f;
  v.z = v.z > 0.f ? v.z : 0.f;
  v.w = v.w > 0.f ? v.w : 0.f;
  ((float4*)h)[i] = v;
}

// ---------------- GEMM: xw2 = h @ W2 (K=128, 32 cols) ----------------
__global__ __launch_bounds__(256) void k_xw2(const float* __restrict__ h,
                                             const float* __restrict__ W2,
                                             float* __restrict__ xw2) {
  __shared__ float Wl[HID*LAT];    // 16KB
  __shared__ float rows[128*HID];  // 64KB
  int tid = threadIdx.x;
  for (int i = tid; i < HID*LAT/4; i += 256)
    ((float4*)Wl)[i] = ((const float4*)W2)[i];
  int rbase = blockIdx.x * 128;
  for (int i = tid; i < 128*HID/4; i += 256) {
    int r = i >> 5, q = i & 31;
    int a = rbase + r;
    ((float4*)rows)[i] = (a < NACT) ? ((const float4*)(h + (size_t)a*HID))[q]
                                    : make_float4(0,0,0,0);
  }
  __syncthreads();
  int w = tid >> 6, l = tid & 63;
  int g = l >> 3, c0 = (l & 7)*4;
  int r0 = w*32 + g*4;
  float4 a0={0,0,0,0}, a1=a0, a2=a0, a3=a0;
  for (int k = 0; k < HID; ++k) {
    float4 wv = *(float4*)&Wl[k*LAT + c0];
    fma4(a0, rows[(r0+0)*HID + k], wv);
    fma4(a1, rows[(r0+1)*HID + k], wv);
    fma4(a2, rows[(r0+2)*HID + k], wv);
    fma4(a3, rows[(r0+3)*HID + k], wv);
  }
  int ar = rbase + r0;
  if (ar+0 < NACT) *(float4*)&xw2[(size_t)(ar+0)*LAT + c0] = a0;
  if (ar+1 < NACT) *(float4*)&xw2[(size_t)(ar+1)*LAT + c0] = a1;
  if (ar+2 < NACT) *(float4*)&xw2[(size_t)(ar+2)*LAT + c0] = a2;
  if (ar+3 < NACT) *(float4*)&xw2[(size_t)(ar+3)*LAT + c0] = a3;
}

// ---------------- self-loop init z ----------------
__global__ __launch_bounds__(256) void k_init_z(const float* __restrict__ dinv,
                                                const float* __restrict__ xw2,
                                                float* __restrict__ z) {
  int i = blockIdx.x*256 + threadIdx.x;  // quad idx; exact
  int a = i >> 3;
  float di = dinv[a]; float s = di*di;
  float4 v = ((const float4*)xw2)[i];
  ((float4*)z)[i] = make_float4(s*v.x, s*v.y, s*v.z, s*v.w);
}

// ---------------- edge scatter layer 2 (thread = 1 col of 1 edge) ----------------
__global__ __launch_bounds__(256) void k_scatter2(const int* __restrict__ pidx,
                                                  const int* __restrict__ midx,
                                                  const float* __restrict__ dinv,
                                                  const float* __restrict__ xw2,
                                                  float* __restrict__ z) {
  int t = blockIdx.x*256 + threadIdx.x;
  int e = t >> 5, c = t & 31;          // exact grid: NE*32 threads
  int m = midx[e], p = pidx[e];
  int sa = NPV + (m < NPV-1 ? m : NPV-1);
  float dp = dinv[p], dsa = dinv[sa];
  atomicAdd(&z[(size_t)p*LAT + c], dsa*dp * xw2[(size_t)sa*LAT + c]);
  if (m < NPV) {
    int da = NPV + m;
    atomicAdd(&z[(size_t)da*LAT + c], dp*dinv[da] * xw2[(size_t)p*LAT + c]);
  }
}

__global__ __launch_bounds__(256) void k_fin_z(const float* __restrict__ b2,
                                               float* __restrict__ z) {
  int i = blockIdx.x*256 + threadIdx.x;
  float4 bv = ((const float4*)b2)[i & 7];
  ((float4*)z)[i] = add4(((float4*)z)[i], bv);
}

// ---------------- decode active nodes and write outputs ----------------
__global__ __launch_bounds__(256) void k_dec_active(const float* __restrict__ z,
                                                    const float* __restrict__ Wd,
                                                    const float* __restrict__ bd,
                                                    float* __restrict__ out) {
  __shared__ float Wl[LAT*DMF];    // 16KB
  __shared__ float rows[32*LAT];   // 4KB
  int tid = threadIdx.x;
  for (int i = tid; i < LAT*DMF/4; i += 256)
    ((float4*)Wl)[i] = ((const float4*)Wd)[i];
  int rbase = blockIdx.x * 32;
  for (int i = tid; i < 32*LAT/4; i += 256)
    ((float4*)rows)[i] = ((const float4*)(z + (size_t)rbase*LAT))[i];
  __syncthreads();
  int w = tid >> 6, l = tid & 63;
  int half = l >> 5, lc = l & 31, c0 = lc*4;
  int r0 = w*8 + half*4;
  float4 a0={0,0,0,0}, a1=a0, a2=a0, a3=a0;
  for (int k = 0; k < LAT; ++k) {
    float4 wv = *(float4*)&Wl[k*DMF + c0];
    fma4(a0, rows[(r0+0)*LAT + k], wv);
    fma4(a1, rows[(r0+1)*LAT + k], wv);
    fma4(a2, rows[(r0+2)*LAT + k], wv);
    fma4(a3, rows[(r0+3)*LAT + k], wv);
  }
  float4 bv = *(const float4*)&bd[c0];
  a0 = add4(a0,bv); a1 = add4(a1,bv); a2 = add4(a2,bv); a3 = add4(a3,bv);
  float4 acc[4] = {a0,a1,a2,a3};
  for (int r = 0; r < 4; ++r) {
    int a = rbase + r0 + r;
    if (a < NPV) {
      *(float4*)&out[(size_t)a*DMF + c0] = acc[r];           // member rows 0..19999
    } else if (c0 < DPF) {
      *(float4*)&out[OUT_PROV + (size_t)(a-NPV)*DPF + c0] = acc[r];  // provider, 64 cols
    }
  }
}

// ---------------- fused MLP for passive member rows 20000..99999 ----------------
__global__ __launch_bounds__(256) void k_passive(const float* __restrict__ xm,
                                                 const float* __restrict__ W1,
                                                 const float* __restrict__ b1,
                                                 const float* __restrict__ W2,
                                                 const float* __restrict__ b2,
                                                 const float* __restrict__ Wd,
                                                 const float* __restrict__ bd,
                                                 float* __restrict__ out) {
  __shared__ float W1l[DMF*HID];   // 64KB
  __shared__ float W2l[HID*LAT];   // 16KB
  __shared__ float Wdl[LAT*DMF];   // 16KB
  __shared__ float xr[32*DMF];     // 16KB
  __shared__ float hb[32*HID];     // 16KB
  __shared__ float zb[32*LAT];     // 4KB
  __shared__ float b1l[HID], b2l[LAT], bdl[DMF];
  int tid = threadIdx.x;
  for (int i = tid; i < DMF*HID/4; i += 256) ((float4*)W1l)[i] = ((const float4*)W1)[i];
  for (int i = tid; i < HID*LAT/4; i += 256) ((float4*)W2l)[i] = ((const float4*)W2)[i];
  for (int i = tid; i < LAT*DMF/4; i += 256) ((float4*)Wdl)[i] = ((const float4*)Wd)[i];
  if (tid < HID) b1l[tid] = b1[tid];
  if (tid < LAT) b2l[tid] = b2[tid];
  if (tid < DMF) bdl[tid] = bd[tid];
  int rbase = NPV + blockIdx.x * 32;   // member rows 20000..99999
  for (int i = tid; i < 32*DMF/4; i += 256)
    ((float4*)xr)[i] = ((const float4*)(xm + (size_t)rbase*DMF))[i];
  __syncthreads();
  int w = tid >> 6, l = tid & 63;
  // phase 1: h = relu(x@W1 + b1)
  {
    int half = l >> 5, lc = l & 31, c0 = lc*4;
    int r0 = w*8 + half*4;
    float4 a0={0,0,0,0}, a1=a0, a2=a0, a3=a0;
    for (int k = 0; k < DMF; ++k) {
      float4 wv = *(float4*)&W1l[k*HID + c0];
      fma4(a0, xr[(r0+0)*DMF + k], wv);
      fma4(a1, xr[(r0+1)*DMF + k], wv);
      fma4(a2, xr[(r0+2)*DMF + k], wv);
      fma4(a3, xr[(r0+3)*DMF + k], wv);
    }
    float4 bv = *(float4*)&b1l[c0];
    float4 acc[4] = {add4(a0,bv), add4(a1,bv), add4(a2,bv), add4(a3,bv)};
    for (int r = 0; r < 4; ++r) {
      float4 v = acc[r];
      v.x = v.x>0.f?v.x:0.f; v.y = v.y>0.f?v.y:0.f; v.z = v.z>0.f?v.z:0.f; v.w = v.w>0.f?v.w:0.f;
      *(float4*)&hb[(r0+r)*HID + c0] = v;
    }
  }
  __syncthreads();
  // phase 2: z = h@W2 + b2
  {
    int g = l >> 3, c0 = (l & 7)*4;
    int row = w*8 + g;
    float4 acc = {0,0,0,0};
    for (int k = 0; k < HID; ++k) {
      float4 wv = *(float4*)&W2l[k*LAT + c0];
      fma4(acc, hb[row*HID + k], wv);
    }
    acc = add4(acc, *(float4*)&b2l[c0]);
    *(float4*)&zb[row*LAT + c0] = acc;
  }
  __syncthreads();
  // phase 3: xhat = z@Wdec + bdec -> out
  {
    int half = l >> 5, lc = l & 31, c0 = lc*4;
    int r0 = w*8 + half*4;
    float4 a0={0,0,0,0}, a1=a0, a2=a0, a3=a0;
    for (int k = 0; k < LAT; ++k) {
      float4 wv = *(float4*)&Wdl[k*DMF + c0];
      fma4(a0, zb[(r0+0)*LAT + k], wv);
      fma4(a1, zb[(r0+1)*LAT + k], wv);
      fma4(a2, zb[(r0+2)*LAT + k], wv);
      fma4(a3, zb[(r0+3)*LAT + k], wv);
    }
    float4 bv = *(float4*)&bdl[c0];
    float4 acc[4] = {add4(a0,bv), add4(a1,bv), add4(a2,bv), add4(a3,bv)};
    for (int r = 0; r < 4; ++r)
      *(float4*)&out[(size_t)(rbase + r0 + r)*DMF + c0] = acc[r];
  }
}

__global__ __launch_bounds__(256) void k_zero_log(float* __restrict__ out) {
  int i = blockIdx.x*256 + threadIdx.x;
  if (i < NE) out[OUT_LOG + i] = 0.f;
}

extern "C" void kernel_launch(void* const* d_in, const int* in_sizes, int n_in,
                              void* d_out, int out_size, void* d_ws, size_t ws_size,
                              hipStream_t stream) {
  const float* xm   = (const float*)d_in[0];
  const float* xp   = (const float*)d_in[1];
  const int*   pidx = (const int*)d_in[2];
  const int*   midx = (const int*)d_in[3];
  const float* W1   = (const float*)d_in[4];
  const float* b1   = (const float*)d_in[5];
  const float* W2   = (const float*)d_in[6];
  const float* b2   = (const float*)d_in[7];
  const float* Wd   = (const float*)d_in[8];
  const float* bd   = (const float*)d_in[9];
  float* out = (float*)d_out;

  // workspace layout (floats): dinv[40000] | xw1[40000*128] | h[40000*128]
  //                            | xw2[40000*32] | z[40000*32]   => 51.36 MB
  if (ws_size < (size_t)51360000) return;
  float* ws   = (float*)d_ws;
  float* dinv = ws;
  float* xw1A = ws + 40000;
  float* hA   = xw1A + (size_t)NACT*HID;
  float* xw2A = hA + (size_t)NACT*HID;
  float* zA   = xw2A + (size_t)NACT*LAT;

  k_deg_init <<<157,    256, 0, stream>>>((int*)dinv);
  k_deg_count<<<1954,   256, 0, stream>>>(pidx, midx, (int*)dinv);
  k_dinv     <<<157,    256, 0, stream>>>(dinv);
  k_xw1      <<<1250,   256, 0, stream>>>(xm, xp, W1, xw1A);
  k_init_h   <<<5000,   256, 0, stream>>>(dinv, xw1A, hA);
  k_scatter1 <<<125000, 256, 0, stream>>>(pidx, midx, dinv, xw1A, hA);
  k_fin_h    <<<5000,   256, 0, stream>>>(b1, hA);
  k_xw2      <<<313,    256, 0, stream>>>(hA, W2, xw2A);
  k_init_z   <<<1250,   256, 0, stream>>>(dinv, xw2A, zA);
  k_scatter2 <<<62500,  256, 0, stream>>>(pidx, midx, dinv, xw2A, zA);
  k_fin_z    <<<1250,   256, 0, stream>>>(b2, zA);
  k_dec_active<<<1250,  256, 0, stream>>>(zA, Wd, bd, out);
  k_passive  <<<2500,   256, 0, stream>>>(xm, W1, b1, W2, b2, Wd, bd, out);
  k_zero_log <<<1954,   256, 0, stream>>>(out);
}

// Round 2
// 419.707 us; speedup vs baseline: 1.9438x; 1.9438x over previous
//
#include <hip/hip_runtime.h>

#define NMN 100000
#define NPV 20000
#define DMF 128
#define DPF 64
#define NE  500000
#define HID 128
#define LAT 32
#define NACT (2*NPV)                  // 40000 edge-active nodes
#define OUT_PROV (NMN*DMF)            // 12,800,000
#define OUT_LOG  (OUT_PROV + NPV*DPF) // 14,080,000

__device__ __forceinline__ void fma4(float4& a, float s, float4 w) {
  a.x += s*w.x; a.y += s*w.y; a.z += s*w.z; a.w += s*w.w;
}
__device__ __forceinline__ float4 add4(float4 a, float4 b) {
  return make_float4(a.x+b.x, a.y+b.y, a.z+b.z, a.w+b.w);
}

// ---------------- degree ----------------
__global__ __launch_bounds__(256) void k_deg_init(int* deg) {
  int i = blockIdx.x*256 + threadIdx.x;
  if (i < NACT) deg[i] = 1;           // self-loop
}

__global__ __launch_bounds__(256) void k_deg_count(const int* __restrict__ pidx,
                                                   const int* __restrict__ midx,
                                                   int* __restrict__ deg) {
  int e = blockIdx.x*256 + threadIdx.x;
  if (e >= NE) return;
  atomicAdd(&deg[pidx[e]], 1);                 // dst = provider_idx (member node)
  int m = midx[e];
  if (m < NPV) atomicAdd(&deg[NPV + m], 1);    // dst = m+NM in-bounds only if m<NP
}

__global__ __launch_bounds__(256) void k_dinv(const int* __restrict__ deg,
                                              float* __restrict__ dinv) {
  int i = blockIdx.x*256 + threadIdx.x;
  if (i < NACT) dinv[i] = rsqrtf((float)deg[i]);
}

// ---------------- exclusive scan of (deg-1) -> off[0..NACT]; zero cursor ----------------
__global__ __launch_bounds__(1024) void k_scan(const int* __restrict__ deg,
                                               int* __restrict__ off,
                                               int* __restrict__ cursor) {
  __shared__ int part[1024];
  int t = threadIdx.x;
  int base = t * 40;
  int cnt[40];
  int s = 0;
  #pragma unroll
  for (int j = 0; j < 40; ++j) {
    int idx = base + j;
    int c = (idx < NACT) ? (deg[idx] - 1) : 0;
    cnt[j] = c; s += c;
  }
  part[t] = s;
  __syncthreads();
  for (int d = 1; d < 1024; d <<= 1) {
    int v = (t >= d) ? part[t - d] : 0;
    __syncthreads();
    part[t] += v;
    __syncthreads();
  }
  int run = (t == 0) ? 0 : part[t - 1];
  #pragma unroll
  for (int j = 0; j < 40; ++j) {
    int idx = base + j;
    if (idx < NACT) { off[idx] = run; cursor[idx] = 0; run += cnt[j]; }
    else if (idx == NACT) { off[idx] = run; }
  }
}

// ---------------- fill CSR (src lists per dst) ----------------
__global__ __launch_bounds__(256) void k_fill(const int* __restrict__ pidx,
                                              const int* __restrict__ midx,
                                              const int* __restrict__ off,
                                              int* __restrict__ cursor,
                                              int* __restrict__ csr) {
  int e = blockIdx.x*256 + threadIdx.x;
  if (e >= NE) return;
  int p = pidx[e], m = midx[e];
  int sa = NPV + (m < NPV ? m : NPV - 1);      // clamped provider-side src
  int pos = atomicAdd(&cursor[p], 1);
  csr[off[p] + pos] = sa;                      // edge into member node p
  if (m < NPV) {
    int da = NPV + m;
    int pos2 = atomicAdd(&cursor[da], 1);
    csr[off[da] + pos2] = p;                   // edge into provider node da
  }
}

// ---------------- GEMM: xw1 = x_active @ W1 (K=128, 128 cols) ----------------
__global__ __launch_bounds__(256) void k_xw1(const float* __restrict__ xm,
                                             const float* __restrict__ xp,
                                             const float* __restrict__ W1,
                                             float* __restrict__ xw1) {
  __shared__ float Wl[DMF*HID];   // 64KB
  __shared__ float rows[32*DMF];  // 16KB
  int tid = threadIdx.x;
  for (int i = tid; i < DMF*HID/4; i += 256)
    ((float4*)Wl)[i] = ((const float4*)W1)[i];
  int rbase = blockIdx.x * 32;
  for (int i = tid; i < 32*DMF/4; i += 256) {
    int r = i >> 5, q = i & 31;
    int a = rbase + r;
    float4 v;
    if (a < NPV) v = ((const float4*)(xm + (size_t)a*DMF))[q];
    else {
      int p = a - NPV;
      v = (q < DPF/4) ? ((const float4*)(xp + (size_t)p*DPF))[q] : make_float4(0,0,0,0);
    }
    ((float4*)rows)[i] = v;
  }
  __syncthreads();
  int w = tid >> 6, l = tid & 63;
  int half = l >> 5, lc = l & 31, c0 = lc*4;
  int r0 = w*8 + half*4;
  float4 a0={0,0,0,0}, a1=a0, a2=a0, a3=a0;
  for (int k = 0; k < DMF; ++k) {
    float4 wv = *(float4*)&Wl[k*HID + c0];
    fma4(a0, rows[(r0+0)*DMF + k], wv);
    fma4(a1, rows[(r0+1)*DMF + k], wv);
    fma4(a2, rows[(r0+2)*DMF + k], wv);
    fma4(a3, rows[(r0+3)*DMF + k], wv);
  }
  int ar = rbase + r0;
  *(float4*)&xw1[(size_t)(ar+0)*HID + c0] = a0;
  *(float4*)&xw1[(size_t)(ar+1)*HID + c0] = a1;
  *(float4*)&xw1[(size_t)(ar+2)*HID + c0] = a2;
  *(float4*)&xw1[(size_t)(ar+3)*HID + c0] = a3;
}

// ---------------- gather layer 1: h = relu(dd*(sum ds*xw1[s] + dd*xw1[dst]) + b1) ----------------
__global__ __launch_bounds__(256) void k_gather1(const int* __restrict__ off,
                                                 const int* __restrict__ csr,
                                                 const float* __restrict__ dinv,
                                                 const float* __restrict__ xw1,
                                                 const float* __restrict__ b1,
                                                 float* __restrict__ h) {
  int tid = threadIdx.x;
  int dst = blockIdx.x*4 + (tid >> 6);   // exact: 10000 blocks * 4 waves
  int l = tid & 63;
  int s0 = off[dst], s1 = off[dst+1];
  float dd = dinv[dst];
  const float2* xb = (const float2*)xw1;
  float2 self = xb[(size_t)dst*64 + l];
  float2 acc = make_float2(dd*self.x, dd*self.y);
  for (int i = s0; i < s1; ++i) {
    int src = csr[i];
    float ds = dinv[src];
    float2 v = xb[(size_t)src*64 + l];
    acc.x += ds*v.x; acc.y += ds*v.y;
  }
  float2 b = ((const float2*)b1)[l];
  float rx = dd*acc.x + b.x;
  float ry = dd*acc.y + b.y;
  rx = rx > 0.f ? rx : 0.f;
  ry = ry > 0.f ? ry : 0.f;
  ((float2*)h)[(size_t)dst*64 + l] = make_float2(rx, ry);
}

// ---------------- GEMM: xw2 = h @ W2 (K=128, 32 cols) ----------------
__global__ __launch_bounds__(256) void k_xw2(const float* __restrict__ h,
                                             const float* __restrict__ W2,
                                             float* __restrict__ xw2) {
  __shared__ float Wl[HID*LAT];    // 16KB
  __shared__ float rows[128*HID];  // 64KB
  int tid = threadIdx.x;
  for (int i = tid; i < HID*LAT/4; i += 256)
    ((float4*)Wl)[i] = ((const float4*)W2)[i];
  int rbase = blockIdx.x * 128;
  for (int i = tid; i < 128*HID/4; i += 256) {
    int r = i >> 5, q = i & 31;
    int a = rbase + r;
    ((float4*)rows)[i] = (a < NACT) ? ((const float4*)(h + (size_t)a*HID))[q]
                                    : make_float4(0,0,0,0);
  }
  __syncthreads();
  int w = tid >> 6, l = tid & 63;
  int g = l >> 3, c0 = (l & 7)*4;
  int r0 = w*32 + g*4;
  float4 a0={0,0,0,0}, a1=a0, a2=a0, a3=a0;
  for (int k = 0; k < HID; ++k) {
    float4 wv = *(float4*)&Wl[k*LAT + c0];
    fma4(a0, rows[(r0+0)*HID + k], wv);
    fma4(a1, rows[(r0+1)*HID + k], wv);
    fma4(a2, rows[(r0+2)*HID + k], wv);
    fma4(a3, rows[(r0+3)*HID + k], wv);
  }
  int ar = rbase + r0;
  if (ar+0 < NACT) *(float4*)&xw2[(size_t)(ar+0)*LAT + c0] = a0;
  if (ar+1 < NACT) *(float4*)&xw2[(size_t)(ar+1)*LAT + c0] = a1;
  if (ar+2 < NACT) *(float4*)&xw2[(size_t)(ar+2)*LAT + c0] = a2;
  if (ar+3 < NACT) *(float4*)&xw2[(size_t)(ar+3)*LAT + c0] = a3;
}

// ---------------- gather layer 2: z = dd*(sum ds*xw2[s] + dd*xw2[dst]) + b2 ----------------
__global__ __launch_bounds__(256) void k_gather2(const int* __restrict__ off,
                                                 const int* __restrict__ csr,
                                                 const float* __restrict__ dinv,
                                                 const float* __restrict__ xw2,
                                                 const float* __restrict__ b2,
                                                 float* __restrict__ z) {
  int tid = threadIdx.x;
  int dst = blockIdx.x*4 + (tid >> 6);   // one wave per dst, 10000 blocks
  int l = tid & 63;
  int half = l >> 5, c = l & 31;
  int s0 = off[dst], s1 = off[dst+1];
  float dd = dinv[dst];
  float acc = 0.f;
  for (int i = s0 + half; i < s1; i += 2) {
    int src = csr[i];
    acc += dinv[src] * xw2[(size_t)src*LAT + c];
  }
  acc += __shfl_xor(acc, 32);
  float res = dd*(acc + dd*xw2[(size_t)dst*LAT + c]) + b2[c];
  if (half == 0) z[(size_t)dst*LAT + c] = res;
}

// ---------------- decode active nodes and write outputs ----------------
__global__ __launch_bounds__(256) void k_dec_active(const float* __restrict__ z,
                                                    const float* __restrict__ Wd,
                                                    const float* __restrict__ bd,
                                                    float* __restrict__ out) {
  __shared__ float Wl[LAT*DMF];    // 16KB
  __shared__ float rows[32*LAT];   // 4KB
  int tid = threadIdx.x;
  for (int i = tid; i < LAT*DMF/4; i += 256)
    ((float4*)Wl)[i] = ((const float4*)Wd)[i];
  int rbase = blockIdx.x * 32;
  for (int i = tid; i < 32*LAT/4; i += 256)
    ((float4*)rows)[i] = ((const float4*)(z + (size_t)rbase*LAT))[i];
  __syncthreads();
  int w = tid >> 6, l = tid & 63;
  int half = l >> 5, lc = l & 31, c0 = lc*4;
  int r0 = w*8 + half*4;
  float4 a0={0,0,0,0}, a1=a0, a2=a0, a3=a0;
  for (int k = 0; k < LAT; ++k) {
    float4 wv = *(float4*)&Wl[k*DMF + c0];
    fma4(a0, rows[(r0+0)*LAT + k], wv);
    fma4(a1, rows[(r0+1)*LAT + k], wv);
    fma4(a2, rows[(r0+2)*LAT + k], wv);
    fma4(a3, rows[(r0+3)*LAT + k], wv);
  }
  float4 bv = *(const float4*)&bd[c0];
  a0 = add4(a0,bv); a1 = add4(a1,bv); a2 = add4(a2,bv); a3 = add4(a3,bv);
  float4 acc[4] = {a0,a1,a2,a3};
  for (int r = 0; r < 4; ++r) {
    int a = rbase + r0 + r;
    if (a < NPV) {
      *(float4*)&out[(size_t)a*DMF + c0] = acc[r];
    } else if (c0 < DPF) {
      *(float4*)&out[OUT_PROV + (size_t)(a-NPV)*DPF + c0] = acc[r];
    }
  }
}

// ---------------- fused MLP for passive member rows 20000..99999 ----------------
__global__ __launch_bounds__(256) void k_passive(const float* __restrict__ xm,
                                                 const float* __restrict__ W1,
                                                 const float* __restrict__ b1,
                                                 const float* __restrict__ W2,
                                                 const float* __restrict__ b2,
                                                 const float* __restrict__ Wd,
                                                 const float* __restrict__ bd,
                                                 float* __restrict__ out) {
  __shared__ float W1l[DMF*HID];   // 64KB
  __shared__ float W2l[HID*LAT];   // 16KB
  __shared__ float Wdl[LAT*DMF];   // 16KB
  __shared__ float xr[32*DMF];     // 16KB
  __shared__ float hb[32*HID];     // 16KB
  __shared__ float zb[32*LAT];     // 4KB
  __shared__ float b1l[HID], b2l[LAT], bdl[DMF];
  int tid = threadIdx.x;
  for (int i = tid; i < DMF*HID/4; i += 256) ((float4*)W1l)[i] = ((const float4*)W1)[i];
  for (int i = tid; i < HID*LAT/4; i += 256) ((float4*)W2l)[i] = ((const float4*)W2)[i];
  for (int i = tid; i < LAT*DMF/4; i += 256) ((float4*)Wdl)[i] = ((const float4*)Wd)[i];
  if (tid < HID) b1l[tid] = b1[tid];
  if (tid < LAT) b2l[tid] = b2[tid];
  if (tid < DMF) bdl[tid] = bd[tid];
  int rbase = NPV + blockIdx.x * 32;
  for (int i = tid; i < 32*DMF/4; i += 256)
    ((float4*)xr)[i] = ((const float4*)(xm + (size_t)rbase*DMF))[i];
  __syncthreads();
  int w = tid >> 6, l = tid & 63;
  {
    int half = l >> 5, lc = l & 31, c0 = lc*4;
    int r0 = w*8 + half*4;
    float4 a0={0,0,0,0}, a1=a0, a2=a0, a3=a0;
    for (int k = 0; k < DMF; ++k) {
      float4 wv = *(float4*)&W1l[k*HID + c0];
      fma4(a0, xr[(r0+0)*DMF + k], wv);
      fma4(a1, xr[(r0+1)*DMF + k], wv);
      fma4(a2, xr[(r0+2)*DMF + k], wv);
      fma4(a3, xr[(r0+3)*DMF + k], wv);
    }
    float4 bv = *(float4*)&b1l[c0];
    float4 acc[4] = {add4(a0,bv), add4(a1,bv), add4(a2,bv), add4(a3,bv)};
    for (int r = 0; r < 4; ++r) {
      float4 v = acc[r];
      v.x = v.x>0.f?v.x:0.f; v.y = v.y>0.f?v.y:0.f; v.z = v.z>0.f?v.z:0.f; v.w = v.w>0.f?v.w:0.f;
      *(float4*)&hb[(r0+r)*HID + c0] = v;
    }
  }
  __syncthreads();
  {
    int g = l >> 3, c0 = (l & 7)*4;
    int row = w*8 + g;
    float4 acc = {0,0,0,0};
    for (int k = 0; k < HID; ++k) {
      float4 wv = *(float4*)&W2l[k*LAT + c0];
      fma4(acc, hb[row*HID + k], wv);
    }
    acc = add4(acc, *(float4*)&b2l[c0]);
    *(float4*)&zb[row*LAT + c0] = acc;
  }
  __syncthreads();
  {
    int half = l >> 5, lc = l & 31, c0 = lc*4;
    int r0 = w*8 + half*4;
    float4 a0={0,0,0,0}, a1=a0, a2=a0, a3=a0;
    for (int k = 0; k < LAT; ++k) {
      float4 wv = *(float4*)&Wdl[k*DMF + c0];
      fma4(a0, zb[(r0+0)*LAT + k], wv);
      fma4(a1, zb[(r0+1)*LAT + k], wv);
      fma4(a2, zb[(r0+2)*LAT + k], wv);
      fma4(a3, zb[(r0+3)*LAT + k], wv);
    }
    float4 bv = *(float4*)&bdl[c0];
    float4 acc[4] = {add4(a0,bv), add4(a1,bv), add4(a2,bv), add4(a3,bv)};
    for (int r = 0; r < 4; ++r)
      *(float4*)&out[(size_t)(rbase + r0 + r)*DMF + c0] = acc[r];
  }
}

__global__ __launch_bounds__(256) void k_zero_log(float* __restrict__ out) {
  int i = blockIdx.x*256 + threadIdx.x;
  if (i < NE) out[OUT_LOG + i] = 0.f;
}

extern "C" void kernel_launch(void* const* d_in, const int* in_sizes, int n_in,
                              void* d_out, int out_size, void* d_ws, size_t ws_size,
                              hipStream_t stream) {
  const float* xm   = (const float*)d_in[0];
  const float* xp   = (const float*)d_in[1];
  const int*   pidx = (const int*)d_in[2];
  const int*   midx = (const int*)d_in[3];
  const float* W1   = (const float*)d_in[4];
  const float* b1   = (const float*)d_in[5];
  const float* W2   = (const float*)d_in[6];
  const float* b2   = (const float*)d_in[7];
  const float* Wd   = (const float*)d_in[8];
  const float* bd   = (const float*)d_in[9];
  float* out = (float*)d_out;

  // ws layout (float units):
  // deg[40000] | dinv[40000] | off[40064] | cursor[40000] | csr[1000000]
  // | xw1A[5120000] (reused as xw2A[1280000] + zA[1280000]) | hA[5120000]
  // total 11,400,064 floats = 45.6 MB
  if (ws_size < (size_t)51360000) return;
  float* ws     = (float*)d_ws;
  int*   deg    = (int*)ws;
  float* dinv   = ws + 40000;
  int*   off    = (int*)(ws + 80000);
  int*   cursor = (int*)(ws + 120064);
  int*   csr    = (int*)(ws + 160064);
  float* xw1A   = ws + 1160064;
  float* hA     = ws + 6280064;
  float* xw2A   = xw1A;                 // xw1 dead after gather1
  float* zA     = xw1A + 1280000;

  k_deg_init  <<<157,   256, 0, stream>>>(deg);
  k_deg_count <<<1954,  256, 0, stream>>>(pidx, midx, deg);
  k_dinv      <<<157,   256, 0, stream>>>(deg, dinv);
  k_scan      <<<1,    1024, 0, stream>>>(deg, off, cursor);
  k_fill      <<<1954,  256, 0, stream>>>(pidx, midx, off, cursor, csr);
  k_xw1       <<<1250,  256, 0, stream>>>(xm, xp, W1, xw1A);
  k_gather1   <<<10000, 256, 0, stream>>>(off, csr, dinv, xw1A, b1, hA);
  k_xw2       <<<313,   256, 0, stream>>>(hA, W2, xw2A);
  k_gather2   <<<10000, 256, 0, stream>>>(off, csr, dinv, xw2A, b2, zA);
  k_dec_active<<<1250,  256, 0, stream>>>(zA, Wd, bd, out);
  k_passive   <<<2500,  256, 0, stream>>>(xm, W1, b1, W2, b2, Wd, bd, out);
  k_zero_log  <<<1954,  256, 0, stream>>>(out);
}

// Round 3
// 392.917 us; speedup vs baseline: 2.0764x; 1.0682x over previous
//
#include <hip/hip_runtime.h>

#define NMN 100000
#define NPV 20000
#define DMF 128
#define DPF 64
#define NE  500000
#define HID 128
#define LAT 32
#define NACT (2*NPV)                  // 40000 edge-active nodes
#define OUT_PROV (NMN*DMF)            // 12,800,000
#define OUT_LOG  (OUT_PROV + NPV*DPF) // 14,080,000
#define XS 132                        // padded row stride (floats) for 128-wide rows
#define ZS 36                         // padded row stride for 32-wide rows

__device__ __forceinline__ void fma4(float4& a, float s, float4 w) {
  a.x += s*w.x; a.y += s*w.y; a.z += s*w.z; a.w += s*w.w;
}
__device__ __forceinline__ float4 add4(float4 a, float4 b) {
  return make_float4(a.x+b.x, a.y+b.y, a.z+b.z, a.w+b.w);
}
__device__ __forceinline__ float4 relu4(float4 v) {
  v.x = v.x>0.f?v.x:0.f; v.y = v.y>0.f?v.y:0.f;
  v.z = v.z>0.f?v.z:0.f; v.w = v.w>0.f?v.w:0.f;
  return v;
}

// ---------------- degree ----------------
__global__ __launch_bounds__(256) void k_deg_init(int* deg) {
  int i = blockIdx.x*256 + threadIdx.x;
  if (i < NACT) deg[i] = 1;           // self-loop
}

__global__ __launch_bounds__(256) void k_deg_count(const int* __restrict__ pidx,
                                                   const int* __restrict__ midx,
                                                   int* __restrict__ deg) {
  int e = blockIdx.x*256 + threadIdx.x;
  if (e >= NE) return;
  atomicAdd(&deg[pidx[e]], 1);                 // dst = provider_idx (member node)
  int m = midx[e];
  if (m < NPV) atomicAdd(&deg[NPV + m], 1);    // dst = m+NM in-bounds only if m<NP
}

__global__ __launch_bounds__(256) void k_dinv(const int* __restrict__ deg,
                                              float* __restrict__ dinv) {
  int i = blockIdx.x*256 + threadIdx.x;
  if (i < NACT) dinv[i] = rsqrtf((float)deg[i]);
}

// ---------------- exclusive scan of (deg-1) -> off[0..NACT]; zero cursor ----------------
__global__ __launch_bounds__(1024) void k_scan(const int* __restrict__ deg,
                                               int* __restrict__ off,
                                               int* __restrict__ cursor) {
  __shared__ int part[1024];
  int t = threadIdx.x;
  int base = t * 40;
  int cnt[40];
  int s = 0;
  #pragma unroll
  for (int j = 0; j < 40; ++j) {
    int idx = base + j;
    int c = (idx < NACT) ? (deg[idx] - 1) : 0;
    cnt[j] = c; s += c;
  }
  part[t] = s;
  __syncthreads();
  for (int d = 1; d < 1024; d <<= 1) {
    int v = (t >= d) ? part[t - d] : 0;
    __syncthreads();
    part[t] += v;
    __syncthreads();
  }
  int run = (t == 0) ? 0 : part[t - 1];
  #pragma unroll
  for (int j = 0; j < 40; ++j) {
    int idx = base + j;
    if (idx < NACT) { off[idx] = run; cursor[idx] = 0; run += cnt[j]; }
    else if (idx == NACT) { off[idx] = run; }
  }
}

// ---------------- fill CSR (src lists per dst) ----------------
__global__ __launch_bounds__(256) void k_fill(const int* __restrict__ pidx,
                                              const int* __restrict__ midx,
                                              const int* __restrict__ off,
                                              int* __restrict__ cursor,
                                              int* __restrict__ csr) {
  int e = blockIdx.x*256 + threadIdx.x;
  if (e >= NE) return;
  int p = pidx[e], m = midx[e];
  int sa = NPV + (m < NPV ? m : NPV - 1);      // clamped provider-side src
  int pos = atomicAdd(&cursor[p], 1);
  csr[off[p] + pos] = sa;                      // edge into member node p
  if (m < NPV) {
    int da = NPV + m;
    int pos2 = atomicAdd(&cursor[da], 1);
    csr[off[da] + pos2] = p;                   // edge into provider node da
  }
}

// ---------------- xw1 = x_active @ W1 : 1024 thr, 128 rows/block ----------------
__global__ __launch_bounds__(1024, 4) void k_xw1(const float* __restrict__ xm,
                                                 const float* __restrict__ xp,
                                                 const float* __restrict__ W1,
                                                 float* __restrict__ xw1) {
  __shared__ float Wl[DMF*HID];       // 64KB
  __shared__ float xr[128*XS];        // 67.5KB, padded stride
  int tid = threadIdx.x;
  for (int i = tid; i < DMF*HID/4; i += 1024)
    ((float4*)Wl)[i] = ((const float4*)W1)[i];
  int rbase = blockIdx.x * 128;
  for (int i = tid; i < 128*DMF/4; i += 1024) {
    int r = i >> 5, q = i & 31;
    int a = rbase + r;
    float4 v = make_float4(0,0,0,0);
    if (a < NPV) v = ((const float4*)(xm + (size_t)a*DMF))[q];
    else if (a < NACT) {
      int p = a - NPV;
      if (q < DPF/4) v = ((const float4*)(xp + (size_t)p*DPF))[q];
    }
    *(float4*)&xr[r*XS + q*4] = v;
  }
  __syncthreads();
  int w = tid >> 6, l = tid & 63;
  int half = l >> 5, lc = l & 31, c0 = lc*4;
  int r0 = w*8 + half*4;
  float4 a0={0,0,0,0}, a1=a0, a2=a0, a3=a0;
  for (int k = 0; k < DMF; ++k) {
    float4 wv = *(float4*)&Wl[k*HID + c0];
    fma4(a0, xr[(r0+0)*XS + k], wv);
    fma4(a1, xr[(r0+1)*XS + k], wv);
    fma4(a2, xr[(r0+2)*XS + k], wv);
    fma4(a3, xr[(r0+3)*XS + k], wv);
  }
  int ar = rbase + r0;
  float4 acc[4] = {a0,a1,a2,a3};
  for (int r = 0; r < 4; ++r)
    if (ar + r < NACT) *(float4*)&xw1[(size_t)(ar+r)*HID + c0] = acc[r];
}

// ---------------- gather layer 1 ----------------
__global__ __launch_bounds__(256) void k_gather1(const int* __restrict__ off,
                                                 const int* __restrict__ csr,
                                                 const float* __restrict__ dinv,
                                                 const float* __restrict__ xw1,
                                                 const float* __restrict__ b1,
                                                 float* __restrict__ h) {
  int tid = threadIdx.x;
  int dst = blockIdx.x*4 + (tid >> 6);   // exact: 10000 blocks * 4 waves
  int l = tid & 63;
  int s0 = off[dst], s1 = off[dst+1];
  float dd = dinv[dst];
  const float2* xb = (const float2*)xw1;
  float2 self = xb[(size_t)dst*64 + l];
  float2 acc = make_float2(dd*self.x, dd*self.y);
  for (int i = s0; i < s1; ++i) {
    int src = csr[i];
    float ds = dinv[src];
    float2 v = xb[(size_t)src*64 + l];
    acc.x += ds*v.x; acc.y += ds*v.y;
  }
  float2 b = ((const float2*)b1)[l];
  float rx = dd*acc.x + b.x;
  float ry = dd*acc.y + b.y;
  rx = rx > 0.f ? rx : 0.f;
  ry = ry > 0.f ? ry : 0.f;
  ((float2*)h)[(size_t)dst*64 + l] = make_float2(rx, ry);
}

// ---------------- xw2 = h @ W2 : 1024 thr, 128 rows/block, W2 via L1 ----------------
__global__ __launch_bounds__(1024, 4) void k_xw2(const float* __restrict__ h,
                                                 const float* __restrict__ W2,
                                                 float* __restrict__ xw2) {
  __shared__ float hr[128*XS];        // 67.5KB
  int tid = threadIdx.x;
  int rbase = blockIdx.x * 128;
  for (int i = tid; i < 128*DMF/4; i += 1024) {
    int r = i >> 5, q = i & 31;
    int a = rbase + r;
    float4 v = (a < NACT) ? ((const float4*)(h + (size_t)a*HID))[q] : make_float4(0,0,0,0);
    *(float4*)&hr[r*XS + q*4] = v;
  }
  __syncthreads();
  int w = tid >> 6, l = tid & 63;
  int g = l >> 3, c0 = (l & 7)*4;
  int row = w*8 + g;                  // wave-private row
  float4 acc = {0,0,0,0};
  #pragma unroll 4
  for (int k = 0; k < HID; ++k) {
    float4 wv = *(const float4*)&W2[k*LAT + c0];   // 16KB, L1-resident
    fma4(acc, hr[row*XS + k], wv);
  }
  int ar = rbase + row;
  if (ar < NACT) *(float4*)&xw2[(size_t)ar*LAT + c0] = acc;
}

// ---------------- gather layer 2 ----------------
__global__ __launch_bounds__(256) void k_gather2(const int* __restrict__ off,
                                                 const int* __restrict__ csr,
                                                 const float* __restrict__ dinv,
                                                 const float* __restrict__ xw2,
                                                 const float* __restrict__ b2,
                                                 float* __restrict__ z) {
  int tid = threadIdx.x;
  int dst = blockIdx.x*4 + (tid >> 6);   // one wave per dst, 10000 blocks
  int l = tid & 63;
  int half = l >> 5, c = l & 31;
  int s0 = off[dst], s1 = off[dst+1];
  float dd = dinv[dst];
  float acc = 0.f;
  for (int i = s0 + half; i < s1; i += 2) {
    int src = csr[i];
    acc += dinv[src] * xw2[(size_t)src*LAT + c];
  }
  acc += __shfl_xor(acc, 32);
  float res = dd*(acc + dd*xw2[(size_t)dst*LAT + c]) + b2[c];
  if (half == 0) z[(size_t)dst*LAT + c] = res;
}

// ---------------- decode active: 1024 thr, 128 rows/block, Wd via L1 ----------------
__global__ __launch_bounds__(1024, 4) void k_dec_active(const float* __restrict__ z,
                                                        const float* __restrict__ Wd,
                                                        const float* __restrict__ bd,
                                                        float* __restrict__ out) {
  __shared__ float zr[128*ZS];        // 18KB
  int tid = threadIdx.x;
  int rbase = blockIdx.x * 128;
  for (int i = tid; i < 128*LAT/4; i += 1024) {
    int r = i >> 3, q = i & 7;
    int a = rbase + r;
    float4 v = (a < NACT) ? ((const float4*)(z + (size_t)a*LAT))[q] : make_float4(0,0,0,0);
    *(float4*)&zr[r*ZS + q*4] = v;
  }
  __syncthreads();
  int w = tid >> 6, l = tid & 63;
  int half = l >> 5, lc = l & 31, c0 = lc*4;
  int r0 = w*8 + half*4;
  float4 a0={0,0,0,0}, a1=a0, a2=a0, a3=a0;
  #pragma unroll 4
  for (int k = 0; k < LAT; ++k) {
    float4 wv = *(const float4*)&Wd[k*DMF + c0];   // 16KB, L1-resident
    fma4(a0, zr[(r0+0)*ZS + k], wv);
    fma4(a1, zr[(r0+1)*ZS + k], wv);
    fma4(a2, zr[(r0+2)*ZS + k], wv);
    fma4(a3, zr[(r0+3)*ZS + k], wv);
  }
  float4 bv = *(const float4*)&bd[c0];
  float4 acc[4] = {add4(a0,bv), add4(a1,bv), add4(a2,bv), add4(a3,bv)};
  for (int r = 0; r < 4; ++r) {
    int a = rbase + r0 + r;
    if (a < NPV) {
      *(float4*)&out[(size_t)a*DMF + c0] = acc[r];
    } else if (a < NACT && c0 < DPF) {
      *(float4*)&out[OUT_PROV + (size_t)(a-NPV)*DPF + c0] = acc[r];
    }
  }
}

// ---------------- fused MLP, passive member rows: 1024 thr, 128 rows ----------------
__global__ __launch_bounds__(1024, 4) void k_passive(const float* __restrict__ xm,
                                                     const float* __restrict__ W1,
                                                     const float* __restrict__ b1,
                                                     const float* __restrict__ W2,
                                                     const float* __restrict__ b2,
                                                     const float* __restrict__ Wd,
                                                     const float* __restrict__ bd,
                                                     float* __restrict__ out) {
  __shared__ float W1l[DMF*HID];      // 64KB
  __shared__ float xh[128*XS];        // 67.5KB : x, overwritten in place by h
  __shared__ float zb[128*ZS];        // 18KB
  int tid = threadIdx.x;
  for (int i = tid; i < DMF*HID/4; i += 1024)
    ((float4*)W1l)[i] = ((const float4*)W1)[i];
  int rbase = NPV + blockIdx.x * 128;   // member rows 20000..99999 (625 blocks exact)
  for (int i = tid; i < 128*DMF/4; i += 1024) {
    int r = i >> 5, q = i & 31;
    float4 v = ((const float4*)(xm + (size_t)(rbase + r)*DMF))[q];
    *(float4*)&xh[r*XS + q*4] = v;
  }
  __syncthreads();                      // the ONLY barrier
  int w = tid >> 6, l = tid & 63;
  int half = l >> 5, lc = l & 31, c0 = lc*4;
  int r0 = w*8 + half*4;                // rows w*8..w*8+7 are wave-private
  // phase 1: h = relu(x@W1 + b1), written in place over x
  {
    float4 a0={0,0,0,0}, a1=a0, a2=a0, a3=a0;
    for (int k = 0; k < DMF; ++k) {
      float4 wv = *(float4*)&W1l[k*HID + c0];
      fma4(a0, xh[(r0+0)*XS + k], wv);
      fma4(a1, xh[(r0+1)*XS + k], wv);
      fma4(a2, xh[(r0+2)*XS + k], wv);
      fma4(a3, xh[(r0+3)*XS + k], wv);
    }
    float4 bv = *(const float4*)&b1[c0];
    float4 acc[4] = {relu4(add4(a0,bv)), relu4(add4(a1,bv)),
                     relu4(add4(a2,bv)), relu4(add4(a3,bv))};
    // program-order per wave: all reads above precede these writes; rows wave-private
    for (int r = 0; r < 4; ++r)
      *(float4*)&xh[(r0+r)*XS + c0] = acc[r];
  }
  // phase 2: z = h@W2 + b2 (row-local per wave, no barrier)
  {
    int g = l >> 3, cz = (l & 7)*4;
    int row = w*8 + g;
    float4 acc = {0,0,0,0};
    #pragma unroll 4
    for (int k = 0; k < HID; ++k) {
      float4 wv = *(const float4*)&W2[k*LAT + cz];   // L1
      fma4(acc, xh[row*XS + k], wv);
    }
    acc = add4(acc, *(const float4*)&b2[cz]);
    *(float4*)&zb[row*ZS + cz] = acc;
  }
  // phase 3: xhat = z@Wdec + bdec -> out (row-local per wave)
  {
    float4 a0={0,0,0,0}, a1=a0, a2=a0, a3=a0;
    #pragma unroll 4
    for (int k = 0; k < LAT; ++k) {
      float4 wv = *(const float4*)&Wd[k*DMF + c0];   // L1
      fma4(a0, zb[(r0+0)*ZS + k], wv);
      fma4(a1, zb[(r0+1)*ZS + k], wv);
      fma4(a2, zb[(r0+2)*ZS + k], wv);
      fma4(a3, zb[(r0+3)*ZS + k], wv);
    }
    float4 bv = *(const float4*)&bd[c0];
    float4 acc[4] = {add4(a0,bv), add4(a1,bv), add4(a2,bv), add4(a3,bv)};
    for (int r = 0; r < 4; ++r)
      *(float4*)&out[(size_t)(rbase + r0 + r)*DMF + c0] = acc[r];
  }
}

__global__ __launch_bounds__(256) void k_zero_log(float* __restrict__ out) {
  int i = blockIdx.x*256 + threadIdx.x;
  if (i < NE) out[OUT_LOG + i] = 0.f;
}

extern "C" void kernel_launch(void* const* d_in, const int* in_sizes, int n_in,
                              void* d_out, int out_size, void* d_ws, size_t ws_size,
                              hipStream_t stream) {
  const float* xm   = (const float*)d_in[0];
  const float* xp   = (const float*)d_in[1];
  const int*   pidx = (const int*)d_in[2];
  const int*   midx = (const int*)d_in[3];
  const float* W1   = (const float*)d_in[4];
  const float* b1   = (const float*)d_in[5];
  const float* W2   = (const float*)d_in[6];
  const float* b2   = (const float*)d_in[7];
  const float* Wd   = (const float*)d_in[8];
  const float* bd   = (const float*)d_in[9];
  float* out = (float*)d_out;

  // ws layout (float units):
  // deg[40000] | dinv[40000] | off[40064] | cursor[40000] | csr[1000000]
  // | xw1A[5120000] (reused as xw2A[1280000] + zA[1280000]) | hA[5120000]
  if (ws_size < (size_t)45600256) return;
  float* ws     = (float*)d_ws;
  int*   deg    = (int*)ws;
  float* dinv   = ws + 40000;
  int*   off    = (int*)(ws + 80000);
  int*   cursor = (int*)(ws + 120064);
  int*   csr    = (int*)(ws + 160064);
  float* xw1A   = ws + 1160064;
  float* hA     = ws + 6280064;
  float* xw2A   = xw1A;                 // xw1 dead after gather1
  float* zA     = xw1A + 1280000;

  k_deg_init  <<<157,   256,  0, stream>>>(deg);
  k_deg_count <<<1954,  256,  0, stream>>>(pidx, midx, deg);
  k_dinv      <<<157,   256,  0, stream>>>(deg, dinv);
  k_scan      <<<1,     1024, 0, stream>>>(deg, off, cursor);
  k_fill      <<<1954,  256,  0, stream>>>(pidx, midx, off, cursor, csr);
  k_xw1       <<<313,   1024, 0, stream>>>(xm, xp, W1, xw1A);
  k_gather1   <<<10000, 256,  0, stream>>>(off, csr, dinv, xw1A, b1, hA);
  k_xw2       <<<313,   1024, 0, stream>>>(hA, W2, xw2A);
  k_gather2   <<<10000, 256,  0, stream>>>(off, csr, dinv, xw2A, b2, zA);
  k_dec_active<<<313,   1024, 0, stream>>>(zA, Wd, bd, out);
  k_passive   <<<625,   1024, 0, stream>>>(xm, W1, b1, W2, b2, Wd, bd, out);
  k_zero_log  <<<1954,  256,  0, stream>>>(out);
}

// Round 4
// 260.348 us; speedup vs baseline: 3.1336x; 1.5092x over previous
//
#include <hip/hip_runtime.h>

#define NMN 100000
#define NPV 20000
#define DMF 128
#define DPF 64
#define NE  500000
#define HID 128
#define LAT 32
#define NACT (2*NPV)                  // 40000 edge-active nodes
#define OUT_PROV (NMN*DMF)            // 12,800,000
#define OUT_LOG  (OUT_PROV + NPV*DPF) // 14,080,000

typedef __attribute__((ext_vector_type(8))) short bf16x8;   // 8 bf16 = 4 VGPR
typedef __attribute__((ext_vector_type(4))) float f32x4;    // MFMA C/D

__device__ __forceinline__ ushort f2bf(float f) {
  unsigned u = __float_as_uint(f);
  u = (u + 0x7fffu + ((u >> 16) & 1u)) >> 16;   // RNE
  return (ushort)u;
}
__device__ __forceinline__ float bf2f(ushort h) {
  return __uint_as_float(((unsigned)h) << 16);
}
__device__ __forceinline__ unsigned pack2(float a, float b) {
  return (unsigned)f2bf(a) | ((unsigned)f2bf(b) << 16);
}

// ---------------- degree ----------------
__global__ __launch_bounds__(256) void k_deg_init(int* deg) {
  int i = blockIdx.x*256 + threadIdx.x;
  if (i < NACT) deg[i] = 1;           // self-loop
}

__global__ __launch_bounds__(256) void k_deg_count(const int* __restrict__ pidx,
                                                   const int* __restrict__ midx,
                                                   int* __restrict__ deg) {
  int e = blockIdx.x*256 + threadIdx.x;
  if (e >= NE) return;
  atomicAdd(&deg[pidx[e]], 1);                 // dst = provider_idx (member node)
  int m = midx[e];
  if (m < NPV) atomicAdd(&deg[NPV + m], 1);    // dst = m+NM in-bounds only if m<NP
}

__global__ __launch_bounds__(256) void k_dinv(const int* __restrict__ deg,
                                              float* __restrict__ dinv) {
  int i = blockIdx.x*256 + threadIdx.x;
  if (i < NACT) dinv[i] = rsqrtf((float)deg[i]);
}

// ---------------- exclusive scan of (deg-1) -> off[0..NACT]; zero cursor ----------------
__global__ __launch_bounds__(1024) void k_scan(const int* __restrict__ deg,
                                               int* __restrict__ off,
                                               int* __restrict__ cursor) {
  __shared__ int part[1024];
  int t = threadIdx.x;
  int base = t * 40;
  int cnt[40];
  int s = 0;
  #pragma unroll
  for (int j = 0; j < 40; ++j) {
    int idx = base + j;
    int c = (idx < NACT) ? (deg[idx] - 1) : 0;
    cnt[j] = c; s += c;
  }
  part[t] = s;
  __syncthreads();
  for (int d = 1; d < 1024; d <<= 1) {
    int v = (t >= d) ? part[t - d] : 0;
    __syncthreads();
    part[t] += v;
    __syncthreads();
  }
  int run = (t == 0) ? 0 : part[t - 1];
  #pragma unroll
  for (int j = 0; j < 40; ++j) {
    int idx = base + j;
    if (idx < NACT) { off[idx] = run; cursor[idx] = 0; run += cnt[j]; }
    else if (idx == NACT) { off[idx] = run; }
  }
}

// ---------------- fill CSR (src lists per dst) ----------------
__global__ __launch_bounds__(256) void k_fill(const int* __restrict__ pidx,
                                              const int* __restrict__ midx,
                                              const int* __restrict__ off,
                                              int* __restrict__ cursor,
                                              int* __restrict__ csr) {
  int e = blockIdx.x*256 + threadIdx.x;
  if (e >= NE) return;
  int p = pidx[e], m = midx[e];
  int sa = NPV + (m < NPV ? m : NPV - 1);      // clamped provider-side src
  int pos = atomicAdd(&cursor[p], 1);
  csr[off[p] + pos] = sa;                      // edge into member node p
  if (m < NPV) {
    int da = NPV + m;
    int pos2 = atomicAdd(&cursor[da], 1);
    csr[off[da] + pos2] = p;                   // edge into provider node da
  }
}

// ---------------- weight prep: bf16 transposed copies ----------------
__global__ __launch_bounds__(256) void k_prep(const float* __restrict__ W1,
                                              const float* __restrict__ W2,
                                              const float* __restrict__ Wd,
                                              ushort* __restrict__ W1t,
                                              ushort* __restrict__ W2t,
                                              ushort* __restrict__ Wdt) {
  int i = blockIdx.x*256 + threadIdx.x;
  if (i < 16384) {                       // W1t[n*128+k] = W1[k][n], (128x128)
    int n = i >> 7, k = i & 127;
    W1t[i] = f2bf(W1[k*HID + n]);
  } else if (i < 20480) {                // W2t[n*128+k] = W2[k][n], n<32,k<128
    int j = i - 16384;
    int n = j >> 7, k = j & 127;
    W2t[j] = f2bf(W2[k*LAT + n]);
  } else if (i < 24576) {                // Wdt[n*32+k] = Wd[k][n], n<128,k<32
    int j = i - 20480;
    int n = j >> 5, k = j & 31;
    Wdt[j] = f2bf(Wd[k*DMF + n]);
  }
}

// ---------------- xw1 = x_active @ W1, MFMA, 64 rows/block ----------------
__global__ __launch_bounds__(256) void k_xw1m(const float* __restrict__ xm,
                                              const float* __restrict__ xp,
                                              const ushort* __restrict__ W1t,
                                              ushort* __restrict__ xw1) {
  __shared__ __align__(16) ushort As[64*136];
  __shared__ __align__(16) ushort Bs[128*136];
  int tid = threadIdx.x;
  int rbase = blockIdx.x * 64;
  for (int i = tid; i < 2048; i += 256) {        // B: [128][128] -> [128][136]
    int n = i >> 4, c = (i & 15) * 8;
    *(uint4*)&Bs[n*136 + c] = *(const uint4*)&W1t[n*128 + c];
  }
  for (int i = tid; i < 1024; i += 256) {        // A: cvt f32->bf16
    int r = i >> 4, c = (i & 15) * 8;
    int a = rbase + r;
    float4 v0 = make_float4(0,0,0,0), v1 = v0;
    if (a < NPV) {
      v0 = *(const float4*)&xm[(size_t)a*DMF + c];
      v1 = *(const float4*)&xm[(size_t)a*DMF + c + 4];
    } else if (c < DPF) {
      int p = a - NPV;
      v0 = *(const float4*)&xp[(size_t)p*DPF + c];
      v1 = *(const float4*)&xp[(size_t)p*DPF + c + 4];
    }
    uint4 u;
    u.x = pack2(v0.x, v0.y); u.y = pack2(v0.z, v0.w);
    u.z = pack2(v1.x, v1.y); u.w = pack2(v1.z, v1.w);
    *(uint4*)&As[r*136 + c] = u;
  }
  __syncthreads();
  int w = tid >> 6, l = tid & 63;
  int mrow = w*16, cl = l & 15, jg = l >> 4;
  bf16x8 af[4];
  #pragma unroll
  for (int s = 0; s < 4; ++s)
    af[s] = *(const bf16x8*)&As[(mrow + cl)*136 + s*32 + jg*8];
  #pragma unroll
  for (int nt = 0; nt < 8; ++nt) {
    f32x4 acc = {0.f,0.f,0.f,0.f};
    #pragma unroll
    for (int s = 0; s < 4; ++s) {
      bf16x8 bf = *(const bf16x8*)&Bs[(nt*16 + cl)*136 + s*32 + jg*8];
      acc = __builtin_amdgcn_mfma_f32_16x16x32_bf16(af[s], bf, acc, 0, 0, 0);
    }
    int col = nt*16 + cl;
    #pragma unroll
    for (int i = 0; i < 4; ++i) {
      int grow = rbase + mrow + jg*4 + i;
      xw1[(size_t)grow*HID + col] = f2bf(acc[i]);
    }
  }
}

// ---------------- gather layer 1 (bf16 in/out, f32 accum) ----------------
__global__ __launch_bounds__(256) void k_gather1(const int* __restrict__ off,
                                                 const int* __restrict__ csr,
                                                 const float* __restrict__ dinv,
                                                 const ushort* __restrict__ xw1,
                                                 const float* __restrict__ b1,
                                                 ushort* __restrict__ h) {
  int tid = threadIdx.x;
  int dst = blockIdx.x*4 + (tid >> 6);   // exact: 10000 blocks * 4 waves
  int l = tid & 63;
  int s0 = off[dst], s1 = off[dst+1];
  float dd = dinv[dst];
  const unsigned* xb = (const unsigned*)xw1;
  unsigned su = xb[(size_t)dst*64 + l];
  float ax = dd * bf2f((ushort)(su & 0xffffu));
  float ay = dd * bf2f((ushort)(su >> 16));
  for (int i = s0; i < s1; ++i) {
    int src = csr[i];
    float ds = dinv[src];
    unsigned u = xb[(size_t)src*64 + l];
    ax += ds * bf2f((ushort)(u & 0xffffu));
    ay += ds * bf2f((ushort)(u >> 16));
  }
  float2 b = ((const float2*)b1)[l];
  float rx = dd*ax + b.x; rx = rx > 0.f ? rx : 0.f;
  float ry = dd*ay + b.y; ry = ry > 0.f ? ry : 0.f;
  ((unsigned*)h)[(size_t)dst*64 + l] = pack2(rx, ry);
}

// ---------------- xw2 = h @ W2, MFMA ----------------
__global__ __launch_bounds__(256) void k_xw2m(const ushort* __restrict__ hg,
                                              const ushort* __restrict__ W2t,
                                              ushort* __restrict__ xw2) {
  __shared__ __align__(16) ushort As[64*136];
  __shared__ __align__(16) ushort Bs[32*136];
  int tid = threadIdx.x;
  int rbase = blockIdx.x * 64;
  for (int i = tid; i < 512; i += 256) {
    int n = i >> 4, c = (i & 15) * 8;
    *(uint4*)&Bs[n*136 + c] = *(const uint4*)&W2t[n*128 + c];
  }
  for (int i = tid; i < 1024; i += 256) {
    int r = i >> 4, c = (i & 15) * 8;
    *(uint4*)&As[r*136 + c] = *(const uint4*)&hg[(size_t)(rbase + r)*HID + c];
  }
  __syncthreads();
  int w = tid >> 6, l = tid & 63;
  int mrow = w*16, cl = l & 15, jg = l >> 4;
  bf16x8 af[4];
  #pragma unroll
  for (int s = 0; s < 4; ++s)
    af[s] = *(const bf16x8*)&As[(mrow + cl)*136 + s*32 + jg*8];
  #pragma unroll
  for (int nt = 0; nt < 2; ++nt) {
    f32x4 acc = {0.f,0.f,0.f,0.f};
    #pragma unroll
    for (int s = 0; s < 4; ++s) {
      bf16x8 bf = *(const bf16x8*)&Bs[(nt*16 + cl)*136 + s*32 + jg*8];
      acc = __builtin_amdgcn_mfma_f32_16x16x32_bf16(af[s], bf, acc, 0, 0, 0);
    }
    int col = nt*16 + cl;
    #pragma unroll
    for (int i = 0; i < 4; ++i) {
      int grow = rbase + mrow + jg*4 + i;
      xw2[(size_t)grow*LAT + col] = f2bf(acc[i]);
    }
  }
}

// ---------------- gather layer 2 (bf16 in/out) ----------------
__global__ __launch_bounds__(256) void k_gather2(const int* __restrict__ off,
                                                 const int* __restrict__ csr,
                                                 const float* __restrict__ dinv,
                                                 const ushort* __restrict__ xw2,
                                                 const float* __restrict__ b2,
                                                 ushort* __restrict__ z) {
  int tid = threadIdx.x;
  int dst = blockIdx.x*4 + (tid >> 6);
  int l = tid & 63;
  int half = l >> 5, c = l & 31;
  int s0 = off[dst], s1 = off[dst+1];
  float dd = dinv[dst];
  float acc = 0.f;
  for (int i = s0 + half; i < s1; i += 2) {
    int src = csr[i];
    acc += dinv[src] * bf2f(xw2[(size_t)src*LAT + c]);
  }
  acc += __shfl_xor(acc, 32);
  float res = dd*(acc + dd*bf2f(xw2[(size_t)dst*LAT + c])) + b2[c];
  if (half == 0) z[(size_t)dst*LAT + c] = f2bf(res);
}

// ---------------- decode active, MFMA (K=32, one k-step) ----------------
__global__ __launch_bounds__(256) void k_decm(const ushort* __restrict__ zg,
                                              const ushort* __restrict__ Wdt,
                                              const float* __restrict__ bd,
                                              float* __restrict__ out) {
  __shared__ __align__(16) ushort As[64*40];
  __shared__ __align__(16) ushort Bs[128*40];
  int tid = threadIdx.x;
  int rbase = blockIdx.x * 64;
  for (int i = tid; i < 512; i += 256) {
    int n = i >> 2, c = (i & 3) * 8;
    *(uint4*)&Bs[n*40 + c] = *(const uint4*)&Wdt[n*32 + c];
  }
  {
    int r = tid >> 2, c = (tid & 3) * 8;   // 256 chunks exactly
    *(uint4*)&As[r*40 + c] = *(const uint4*)&zg[(size_t)(rbase + r)*LAT + c];
  }
  __syncthreads();
  int w = tid >> 6, l = tid & 63;
  int mrow = w*16, cl = l & 15, jg = l >> 4;
  bf16x8 af = *(const bf16x8*)&As[(mrow + cl)*40 + jg*8];
  #pragma unroll
  for (int nt = 0; nt < 8; ++nt) {
    f32x4 acc = {0.f,0.f,0.f,0.f};
    bf16x8 bf = *(const bf16x8*)&Bs[(nt*16 + cl)*40 + jg*8];
    acc = __builtin_amdgcn_mfma_f32_16x16x32_bf16(af, bf, acc, 0, 0, 0);
    int col = nt*16 + cl;
    float bv = bd[col];
    #pragma unroll
    for (int i = 0; i < 4; ++i) {
      int grow = rbase + mrow + jg*4 + i;
      float v = acc[i] + bv;
      if (grow < NPV) out[(size_t)grow*DMF + col] = v;
      else if (col < DPF) out[OUT_PROV + (size_t)(grow - NPV)*DPF + col] = v;
    }
  }
}

// ---------------- fused passive MLP, MFMA, 64 rows/block ----------------
__global__ __launch_bounds__(256) void k_passm(const float* __restrict__ xm,
                                               const ushort* __restrict__ W1t,
                                               const float* __restrict__ b1,
                                               const ushort* __restrict__ W2t,
                                               const float* __restrict__ b2,
                                               const ushort* __restrict__ Wdt,
                                               const float* __restrict__ bd,
                                               float* __restrict__ out) {
  __shared__ __align__(16) ushort XH[64*136];   // x, overwritten by h (wave-private rows)
  __shared__ __align__(16) ushort ZB[64*40];
  __shared__ __align__(16) ushort B1s[128*136];
  __shared__ __align__(16) ushort B2s[32*136];
  __shared__ __align__(16) ushort Bds[128*40];
  int tid = threadIdx.x;
  int rbase = NPV + blockIdx.x * 64;            // member rows 20000..99999
  for (int i = tid; i < 2048; i += 256) {
    int n = i >> 4, c = (i & 15) * 8;
    *(uint4*)&B1s[n*136 + c] = *(const uint4*)&W1t[n*128 + c];
  }
  for (int i = tid; i < 512; i += 256) {
    int n = i >> 4, c = (i & 15) * 8;
    *(uint4*)&B2s[n*136 + c] = *(const uint4*)&W2t[n*128 + c];
  }
  for (int i = tid; i < 512; i += 256) {
    int n = i >> 2, c = (i & 3) * 8;
    *(uint4*)&Bds[n*40 + c] = *(const uint4*)&Wdt[n*32 + c];
  }
  for (int i = tid; i < 1024; i += 256) {
    int r = i >> 4, c = (i & 15) * 8;
    float4 v0 = *(const float4*)&xm[(size_t)(rbase + r)*DMF + c];
    float4 v1 = *(const float4*)&xm[(size_t)(rbase + r)*DMF + c + 4];
    uint4 u;
    u.x = pack2(v0.x, v0.y); u.y = pack2(v0.z, v0.w);
    u.z = pack2(v1.x, v1.y); u.w = pack2(v1.z, v1.w);
    *(uint4*)&XH[r*136 + c] = u;
  }
  __syncthreads();                              // the ONLY barrier
  int w = tid >> 6, l = tid & 63;
  int mrow = w*16, cl = l & 15, jg = l >> 4;
  // phase 1: h = relu(x@W1 + b1) -> XH in place (rows wave-private; A preloaded)
  {
    bf16x8 af[4];
    #pragma unroll
    for (int s = 0; s < 4; ++s)
      af[s] = *(const bf16x8*)&XH[(mrow + cl)*136 + s*32 + jg*8];
    #pragma unroll
    for (int nt = 0; nt < 8; ++nt) {
      f32x4 acc = {0.f,0.f,0.f,0.f};
      #pragma unroll
      for (int s = 0; s < 4; ++s) {
        bf16x8 bf = *(const bf16x8*)&B1s[(nt*16 + cl)*136 + s*32 + jg*8];
        acc = __builtin_amdgcn_mfma_f32_16x16x32_bf16(af[s], bf, acc, 0, 0, 0);
      }
      int col = nt*16 + cl;
      float bv = b1[col];
      #pragma unroll
      for (int i = 0; i < 4; ++i) {
        float v = acc[i] + bv;
        v = v > 0.f ? v : 0.f;
        XH[(mrow + jg*4 + i)*136 + col] = f2bf(v);
      }
    }
  }
  // phase 2: z = h@W2 + b2 -> ZB
  {
    bf16x8 af[4];
    #pragma unroll
    for (int s = 0; s < 4; ++s)
      af[s] = *(const bf16x8*)&XH[(mrow + cl)*136 + s*32 + jg*8];
    #pragma unroll
    for (int nt = 0; nt < 2; ++nt) {
      f32x4 acc = {0.f,0.f,0.f,0.f};
      #pragma unroll
      for (int s = 0; s < 4; ++s) {
        bf16x8 bf = *(const bf16x8*)&B2s[(nt*16 + cl)*136 + s*32 + jg*8];
        acc = __builtin_amdgcn_mfma_f32_16x16x32_bf16(af[s], bf, acc, 0, 0, 0);
      }
      int col = nt*16 + cl;
      float bv = b2[col];
      #pragma unroll
      for (int i = 0; i < 4; ++i)
        ZB[(mrow + jg*4 + i)*40 + col] = f2bf(acc[i] + bv);
    }
  }
  // phase 3: xhat = z@Wd + bd -> out
  {
    bf16x8 af = *(const bf16x8*)&ZB[(mrow + cl)*40 + jg*8];
    #pragma unroll
    for (int nt = 0; nt < 8; ++nt) {
      f32x4 acc = {0.f,0.f,0.f,0.f};
      bf16x8 bf = *(const bf16x8*)&Bds[(nt*16 + cl)*40 + jg*8];
      acc = __builtin_amdgcn_mfma_f32_16x16x32_bf16(af, bf, acc, 0, 0, 0);
      int col = nt*16 + cl;
      float bv = bd[col];
      #pragma unroll
      for (int i = 0; i < 4; ++i) {
        size_t grow = rbase + mrow + jg*4 + i;
        out[grow*DMF + col] = acc[i] + bv;
      }
    }
  }
}

__global__ __launch_bounds__(256) void k_zero_log(float* __restrict__ out) {
  int i = blockIdx.x*256 + threadIdx.x;
  if (i < NE) out[OUT_LOG + i] = 0.f;
}

extern "C" void kernel_launch(void* const* d_in, const int* in_sizes, int n_in,
                              void* d_out, int out_size, void* d_ws, size_t ws_size,
                              hipStream_t stream) {
  const float* xm   = (const float*)d_in[0];
  const float* xp   = (const float*)d_in[1];
  const int*   pidx = (const int*)d_in[2];
  const int*   midx = (const int*)d_in[3];
  const float* W1   = (const float*)d_in[4];
  const float* b1   = (const float*)d_in[5];
  const float* W2   = (const float*)d_in[6];
  const float* b2   = (const float*)d_in[7];
  const float* Wd   = (const float*)d_in[8];
  const float* bd   = (const float*)d_in[9];
  float* out = (float*)d_out;

  // ws layout (bytes):
  // deg[160000] dinv[160000] off[160256] cursor[160000] csr[4000000]
  // W1t[32768] W2t[8192] Wdt[8192]
  // xw1[10240000] h[10240000] xw2[2560000] z[2560000]   => 30,289,408 B
  if (ws_size < (size_t)30289408) return;
  char* W = (char*)d_ws;
  int*    deg    = (int*)(W + 0);
  float*  dinv   = (float*)(W + 160000);
  int*    off    = (int*)(W + 320000);
  int*    cursor = (int*)(W + 480256);
  int*    csr    = (int*)(W + 640256);
  ushort* W1t    = (ushort*)(W + 4640256);
  ushort* W2t    = (ushort*)(W + 4673024);
  ushort* Wdt    = (ushort*)(W + 4681216);
  ushort* xw1g   = (ushort*)(W + 4689408);
  ushort* hg     = (ushort*)(W + 14929408);
  ushort* xw2g   = (ushort*)(W + 25169408);
  ushort* zg     = (ushort*)(W + 27729408);

  k_prep      <<<96,    256,  0, stream>>>(W1, W2, Wd, W1t, W2t, Wdt);
  k_deg_init  <<<157,   256,  0, stream>>>(deg);
  k_deg_count <<<1954,  256,  0, stream>>>(pidx, midx, deg);
  k_dinv      <<<157,   256,  0, stream>>>(deg, dinv);
  k_scan      <<<1,     1024, 0, stream>>>(deg, off, cursor);
  k_fill      <<<1954,  256,  0, stream>>>(pidx, midx, off, cursor, csr);
  k_xw1m      <<<625,   256,  0, stream>>>(xm, xp, W1t, xw1g);
  k_gather1   <<<10000, 256,  0, stream>>>(off, csr, dinv, xw1g, b1, hg);
  k_xw2m      <<<625,   256,  0, stream>>>(hg, W2t, xw2g);
  k_gather2   <<<10000, 256,  0, stream>>>(off, csr, dinv, xw2g, b2, zg);
  k_decm      <<<625,   256,  0, stream>>>(zg, Wdt, bd, out);
  k_passm     <<<1250,  256,  0, stream>>>(xm, W1t, b1, W2t, b2, Wdt, bd, out);
  k_zero_log  <<<1954,  256,  0, stream>>>(out);
}

// Round 5
// 203.062 us; speedup vs baseline: 4.0177x; 1.2821x over previous
//
#include <hip/hip_runtime.h>

#define NMN 100000
#define NPV 20000
#define DMF 128
#define DPF 64
#define NE  500000
#define HID 128
#define LAT 32
#define NACT (2*NPV)                  // 40000 edge-active nodes
#define OUT_PROV (NMN*DMF)            // 12,800,000
#define OUT_LOG  (OUT_PROV + NPV*DPF) // 14,080,000

typedef __attribute__((ext_vector_type(8))) short bf16x8;   // 8 bf16 = 4 VGPR
typedef __attribute__((ext_vector_type(4))) float f32x4;    // MFMA C/D

__device__ __forceinline__ ushort f2bf(float f) {
  unsigned u = __float_as_uint(f);
  u = (u + 0x7fffu + ((u >> 16) & 1u)) >> 16;   // RNE
  return (ushort)u;
}
__device__ __forceinline__ float bf2f(ushort h) {
  return __uint_as_float(((unsigned)h) << 16);
}
__device__ __forceinline__ unsigned pack2(float a, float b) {
  return (unsigned)f2bf(a) | ((unsigned)f2bf(b) << 16);
}

// ---------------- degree ----------------
__global__ __launch_bounds__(256) void k_deg_init(int* deg) {
  int i = blockIdx.x*256 + threadIdx.x;
  if (i < NACT) deg[i] = 1;           // self-loop
}

__global__ __launch_bounds__(256) void k_deg_count(const int* __restrict__ pidx,
                                                   const int* __restrict__ midx,
                                                   int* __restrict__ deg) {
  int e = blockIdx.x*256 + threadIdx.x;
  if (e >= NE) return;
  atomicAdd(&deg[pidx[e]], 1);                 // dst = provider_idx (member node)
  int m = midx[e];
  if (m < NPV) atomicAdd(&deg[NPV + m], 1);    // dst = m+NM in-bounds only if m<NP
}

// ---------------- scan stage A: block-inclusive scan of (deg-1); fold dinv ----------------
__global__ __launch_bounds__(1024) void k_scan1(const int* __restrict__ deg,
                                                float* __restrict__ dinv,
                                                int* __restrict__ inc,
                                                int* __restrict__ bsum) {
  int tid = threadIdx.x;
  int i = blockIdx.x*1024 + tid;
  int val = 0;
  if (i < NACT) {
    int d = deg[i];
    val = d - 1;
    dinv[i] = rsqrtf((float)d);
  }
  int lane = tid & 63, wv = tid >> 6;
  int x = val;
  #pragma unroll
  for (int d = 1; d < 64; d <<= 1) {
    int o = __shfl_up(x, d);
    if (lane >= d) x += o;
  }
  __shared__ int wsums[16];
  if (lane == 63) wsums[wv] = x;
  __syncthreads();
  if (tid == 0) {
    int run = 0;
    #pragma unroll
    for (int j = 0; j < 16; ++j) { int t = wsums[j]; wsums[j] = run; run += t; }
  }
  __syncthreads();
  int incl = x + wsums[wv];
  inc[i] = incl;
  if (tid == 1023) bsum[blockIdx.x] = incl;
}

// ---------------- scan stage B: scan 40 block sums ----------------
__global__ __launch_bounds__(64) void k_scan2(const int* __restrict__ bsum,
                                              int* __restrict__ boff,
                                              int* __restrict__ off) {
  int t = threadIdx.x;
  int v = (t < 40) ? bsum[t] : 0;
  int x = v;
  #pragma unroll
  for (int d = 1; d < 64; d <<= 1) {
    int o = __shfl_up(x, d);
    if (t >= d) x += o;
  }
  if (t < 40) boff[t] = x - v;       // exclusive
  if (t == 39) off[NACT] = x;        // grand total
}

// ---------------- scan stage C: finalize off, zero cursor ----------------
__global__ __launch_bounds__(1024) void k_scan3(const int* __restrict__ deg,
                                                const int* __restrict__ inc,
                                                const int* __restrict__ boff,
                                                int* __restrict__ off,
                                                int* __restrict__ cursor) {
  int i = blockIdx.x*1024 + threadIdx.x;
  if (i < NACT) {
    int val = deg[i] - 1;
    off[i] = boff[blockIdx.x] + inc[i] - val;
    cursor[i] = 0;
  }
}

// ---------------- fill CSR (src lists per dst) ----------------
__global__ __launch_bounds__(256) void k_fill(const int* __restrict__ pidx,
                                              const int* __restrict__ midx,
                                              const int* __restrict__ off,
                                              int* __restrict__ cursor,
                                              int* __restrict__ csr) {
  int e = blockIdx.x*256 + threadIdx.x;
  if (e >= NE) return;
  int p = pidx[e], m = midx[e];
  int sa = NPV + (m < NPV ? m : NPV - 1);      // clamped provider-side src
  int pos = atomicAdd(&cursor[p], 1);
  csr[off[p] + pos] = sa;                      // edge into member node p
  if (m < NPV) {
    int da = NPV + m;
    int pos2 = atomicAdd(&cursor[da], 1);
    csr[off[da] + pos2] = p;                   // edge into provider node da
  }
}

// ---------------- weight prep (bf16 transposed) + zero edge logits ----------------
__global__ __launch_bounds__(256) void k_prep(const float* __restrict__ W1,
                                              const float* __restrict__ W2,
                                              const float* __restrict__ Wd,
                                              ushort* __restrict__ W1t,
                                              ushort* __restrict__ W2t,
                                              ushort* __restrict__ Wdt,
                                              float* __restrict__ out) {
  int i = blockIdx.x*256 + threadIdx.x;
  if (i < 16384) {                       // W1t[n*128+k] = W1[k][n]
    int n = i >> 7, k = i & 127;
    W1t[i] = f2bf(W1[k*HID + n]);
  } else if (i < 20480) {                // W2t[n*128+k] = W2[k][n]
    int j = i - 16384;
    int n = j >> 7, k = j & 127;
    W2t[j] = f2bf(W2[k*LAT + n]);
  } else if (i < 24576) {                // Wdt[n*32+k] = Wd[k][n]
    int j = i - 20480;
    int n = j >> 5, k = j & 31;
    Wdt[j] = f2bf(Wd[k*DMF + n]);
  }
  if (i < NE) out[OUT_LOG + i] = 0.f;
}

// ---------------- xw1 = x_active @ W1, MFMA, 64 rows/block ----------------
__global__ __launch_bounds__(256) void k_xw1m(const float* __restrict__ xm,
                                              const float* __restrict__ xp,
                                              const ushort* __restrict__ W1t,
                                              ushort* __restrict__ xw1) {
  __shared__ __align__(16) ushort As[64*136];
  __shared__ __align__(16) ushort Bs[128*136];
  int tid = threadIdx.x;
  int rbase = blockIdx.x * 64;
  for (int i = tid; i < 2048; i += 256) {
    int n = i >> 4, c = (i & 15) * 8;
    *(uint4*)&Bs[n*136 + c] = *(const uint4*)&W1t[n*128 + c];
  }
  for (int i = tid; i < 1024; i += 256) {
    int r = i >> 4, c = (i & 15) * 8;
    int a = rbase + r;
    float4 v0 = make_float4(0,0,0,0), v1 = v0;
    if (a < NPV) {
      v0 = *(const float4*)&xm[(size_t)a*DMF + c];
      v1 = *(const float4*)&xm[(size_t)a*DMF + c + 4];
    } else if (c < DPF) {
      int p = a - NPV;
      v0 = *(const float4*)&xp[(size_t)p*DPF + c];
      v1 = *(const float4*)&xp[(size_t)p*DPF + c + 4];
    }
    uint4 u;
    u.x = pack2(v0.x, v0.y); u.y = pack2(v0.z, v0.w);
    u.z = pack2(v1.x, v1.y); u.w = pack2(v1.z, v1.w);
    *(uint4*)&As[r*136 + c] = u;
  }
  __syncthreads();
  int w = tid >> 6, l = tid & 63;
  int mrow = w*16, cl = l & 15, jg = l >> 4;
  bf16x8 af[4];
  #pragma unroll
  for (int s = 0; s < 4; ++s)
    af[s] = *(const bf16x8*)&As[(mrow + cl)*136 + s*32 + jg*8];
  #pragma unroll
  for (int nt = 0; nt < 8; ++nt) {
    f32x4 acc = {0.f,0.f,0.f,0.f};
    #pragma unroll
    for (int s = 0; s < 4; ++s) {
      bf16x8 bf = *(const bf16x8*)&Bs[(nt*16 + cl)*136 + s*32 + jg*8];
      acc = __builtin_amdgcn_mfma_f32_16x16x32_bf16(af[s], bf, acc, 0, 0, 0);
    }
    int col = nt*16 + cl;
    #pragma unroll
    for (int i = 0; i < 4; ++i) {
      int grow = rbase + mrow + jg*4 + i;
      xw1[(size_t)grow*HID + col] = f2bf(acc[i]);
    }
  }
}

// ---------------- gather layer 1 (bf16 in/out, f32 accum) ----------------
__global__ __launch_bounds__(256) void k_gather1(const int* __restrict__ off,
                                                 const int* __restrict__ csr,
                                                 const float* __restrict__ dinv,
                                                 const ushort* __restrict__ xw1,
                                                 const float* __restrict__ b1,
                                                 ushort* __restrict__ h) {
  int tid = threadIdx.x;
  int dst = blockIdx.x*4 + (tid >> 6);   // exact: 10000 blocks * 4 waves
  int l = tid & 63;
  int s0 = off[dst], s1 = off[dst+1];
  float dd = dinv[dst];
  const unsigned* xb = (const unsigned*)xw1;
  unsigned su = xb[(size_t)dst*64 + l];
  float ax = dd * bf2f((ushort)(su & 0xffffu));
  float ay = dd * bf2f((ushort)(su >> 16));
  for (int i = s0; i < s1; ++i) {
    int src = csr[i];
    float ds = dinv[src];
    unsigned u = xb[(size_t)src*64 + l];
    ax += ds * bf2f((ushort)(u & 0xffffu));
    ay += ds * bf2f((ushort)(u >> 16));
  }
  float2 b = ((const float2*)b1)[l];
  float rx = dd*ax + b.x; rx = rx > 0.f ? rx : 0.f;
  float ry = dd*ay + b.y; ry = ry > 0.f ? ry : 0.f;
  ((unsigned*)h)[(size_t)dst*64 + l] = pack2(rx, ry);
}

// ---------------- xw2 = h @ W2, MFMA ----------------
__global__ __launch_bounds__(256) void k_xw2m(const ushort* __restrict__ hg,
                                              const ushort* __restrict__ W2t,
                                              ushort* __restrict__ xw2) {
  __shared__ __align__(16) ushort As[64*136];
  __shared__ __align__(16) ushort Bs[32*136];
  int tid = threadIdx.x;
  int rbase = blockIdx.x * 64;
  for (int i = tid; i < 512; i += 256) {
    int n = i >> 4, c = (i & 15) * 8;
    *(uint4*)&Bs[n*136 + c] = *(const uint4*)&W2t[n*128 + c];
  }
  for (int i = tid; i < 1024; i += 256) {
    int r = i >> 4, c = (i & 15) * 8;
    *(uint4*)&As[r*136 + c] = *(const uint4*)&hg[(size_t)(rbase + r)*HID + c];
  }
  __syncthreads();
  int w = tid >> 6, l = tid & 63;
  int mrow = w*16, cl = l & 15, jg = l >> 4;
  bf16x8 af[4];
  #pragma unroll
  for (int s = 0; s < 4; ++s)
    af[s] = *(const bf16x8*)&As[(mrow + cl)*136 + s*32 + jg*8];
  #pragma unroll
  for (int nt = 0; nt < 2; ++nt) {
    f32x4 acc = {0.f,0.f,0.f,0.f};
    #pragma unroll
    for (int s = 0; s < 4; ++s) {
      bf16x8 bf = *(const bf16x8*)&Bs[(nt*16 + cl)*136 + s*32 + jg*8];
      acc = __builtin_amdgcn_mfma_f32_16x16x32_bf16(af[s], bf, acc, 0, 0, 0);
    }
    int col = nt*16 + cl;
    #pragma unroll
    for (int i = 0; i < 4; ++i) {
      int grow = rbase + mrow + jg*4 + i;
      xw2[(size_t)grow*LAT + col] = f2bf(acc[i]);
    }
  }
}

// ---------------- gather layer 2 (bf16 in/out) ----------------
__global__ __launch_bounds__(256) void k_gather2(const int* __restrict__ off,
                                                 const int* __restrict__ csr,
                                                 const float* __restrict__ dinv,
                                                 const ushort* __restrict__ xw2,
                                                 const float* __restrict__ b2,
                                                 ushort* __restrict__ z) {
  int tid = threadIdx.x;
  int dst = blockIdx.x*4 + (tid >> 6);
  int l = tid & 63;
  int half = l >> 5, c = l & 31;
  int s0 = off[dst], s1 = off[dst+1];
  float dd = dinv[dst];
  float acc = 0.f;
  for (int i = s0 + half; i < s1; i += 2) {
    int src = csr[i];
    acc += dinv[src] * bf2f(xw2[(size_t)src*LAT + c]);
  }
  acc += __shfl_xor(acc, 32);
  float res = dd*(acc + dd*bf2f(xw2[(size_t)dst*LAT + c])) + b2[c];
  if (half == 0) z[(size_t)dst*LAT + c] = f2bf(res);
}

// ---------------- decode active, MFMA (K=32, one k-step) ----------------
__global__ __launch_bounds__(256) void k_decm(const ushort* __restrict__ zg,
                                              const ushort* __restrict__ Wdt,
                                              const float* __restrict__ bd,
                                              float* __restrict__ out) {
  __shared__ __align__(16) ushort As[64*40];
  __shared__ __align__(16) ushort Bs[128*40];
  int tid = threadIdx.x;
  int rbase = blockIdx.x * 64;
  for (int i = tid; i < 512; i += 256) {
    int n = i >> 2, c = (i & 3) * 8;
    *(uint4*)&Bs[n*40 + c] = *(const uint4*)&Wdt[n*32 + c];
  }
  {
    int r = tid >> 2, c = (tid & 3) * 8;   // 256 chunks exactly
    *(uint4*)&As[r*40 + c] = *(const uint4*)&zg[(size_t)(rbase + r)*LAT + c];
  }
  __syncthreads();
  int w = tid >> 6, l = tid & 63;
  int mrow = w*16, cl = l & 15, jg = l >> 4;
  bf16x8 af = *(const bf16x8*)&As[(mrow + cl)*40 + jg*8];
  #pragma unroll
  for (int nt = 0; nt < 8; ++nt) {
    f32x4 acc = {0.f,0.f,0.f,0.f};
    bf16x8 bf = *(const bf16x8*)&Bs[(nt*16 + cl)*40 + jg*8];
    acc = __builtin_amdgcn_mfma_f32_16x16x32_bf16(af, bf, acc, 0, 0, 0);
    int col = nt*16 + cl;
    float bv = bd[col];
    #pragma unroll
    for (int i = 0; i < 4; ++i) {
      int grow = rbase + mrow + jg*4 + i;
      float v = acc[i] + bv;
      if (grow < NPV) out[(size_t)grow*DMF + col] = v;
      else if (col < DPF) out[OUT_PROV + (size_t)(grow - NPV)*DPF + col] = v;
    }
  }
}

// ---------------- fused passive MLP, MFMA, 64 rows/block ----------------
__global__ __launch_bounds__(256) void k_passm(const float* __restrict__ xm,
                                               const ushort* __restrict__ W1t,
                                               const float* __restrict__ b1,
                                               const ushort* __restrict__ W2t,
                                               const float* __restrict__ b2,
                                               const ushort* __restrict__ Wdt,
                                               const float* __restrict__ bd,
                                               float* __restrict__ out) {
  __shared__ __align__(16) ushort XH[64*136];   // x, overwritten by h (wave-private rows)
  __shared__ __align__(16) ushort ZB[64*40];
  __shared__ __align__(16) ushort B1s[128*136];
  __shared__ __align__(16) ushort B2s[32*136];
  __shared__ __align__(16) ushort Bds[128*40];
  int tid = threadIdx.x;
  int rbase = NPV + blockIdx.x * 64;            // member rows 20000..99999
  for (int i = tid; i < 2048; i += 256) {
    int n = i >> 4, c = (i & 15) * 8;
    *(uint4*)&B1s[n*136 + c] = *(const uint4*)&W1t[n*128 + c];
  }
  for (int i = tid; i < 512; i += 256) {
    int n = i >> 4, c = (i & 15) * 8;
    *(uint4*)&B2s[n*136 + c] = *(const uint4*)&W2t[n*128 + c];
  }
  for (int i = tid; i < 512; i += 256) {
    int n = i >> 2, c = (i & 3) * 8;
    *(uint4*)&Bds[n*40 + c] = *(const uint4*)&Wdt[n*32 + c];
  }
  for (int i = tid; i < 1024; i += 256) {
    int r = i >> 4, c = (i & 15) * 8;
    float4 v0 = *(const float4*)&xm[(size_t)(rbase + r)*DMF + c];
    float4 v1 = *(const float4*)&xm[(size_t)(rbase + r)*DMF + c + 4];
    uint4 u;
    u.x = pack2(v0.x, v0.y); u.y = pack2(v0.z, v0.w);
    u.z = pack2(v1.x, v1.y); u.w = pack2(v1.z, v1.w);
    *(uint4*)&XH[r*136 + c] = u;
  }
  __syncthreads();                              // the ONLY barrier
  int w = tid >> 6, l = tid & 63;
  int mrow = w*16, cl = l & 15, jg = l >> 4;
  // phase 1: h = relu(x@W1 + b1) -> XH in place (rows wave-private; A preloaded)
  {
    bf16x8 af[4];
    #pragma unroll
    for (int s = 0; s < 4; ++s)
      af[s] = *(const bf16x8*)&XH[(mrow + cl)*136 + s*32 + jg*8];
    #pragma unroll
    for (int nt = 0; nt < 8; ++nt) {
      f32x4 acc = {0.f,0.f,0.f,0.f};
      #pragma unroll
      for (int s = 0; s < 4; ++s) {
        bf16x8 bf = *(const bf16x8*)&B1s[(nt*16 + cl)*136 + s*32 + jg*8];
        acc = __builtin_amdgcn_mfma_f32_16x16x32_bf16(af[s], bf, acc, 0, 0, 0);
      }
      int col = nt*16 + cl;
      float bv = b1[col];
      #pragma unroll
      for (int i = 0; i < 4; ++i) {
        float v = acc[i] + bv;
        v = v > 0.f ? v : 0.f;
        XH[(mrow + jg*4 + i)*136 + col] = f2bf(v);
      }
    }
  }
  // phase 2: z = h@W2 + b2 -> ZB
  {
    bf16x8 af[4];
    #pragma unroll
    for (int s = 0; s < 4; ++s)
      af[s] = *(const bf16x8*)&XH[(mrow + cl)*136 + s*32 + jg*8];
    #pragma unroll
    for (int nt = 0; nt < 2; ++nt) {
      f32x4 acc = {0.f,0.f,0.f,0.f};
      #pragma unroll
      for (int s = 0; s < 4; ++s) {
        bf16x8 bf = *(const bf16x8*)&B2s[(nt*16 + cl)*136 + s*32 + jg*8];
        acc = __builtin_amdgcn_mfma_f32_16x16x32_bf16(af[s], bf, acc, 0, 0, 0);
      }
      int col = nt*16 + cl;
      float bv = b2[col];
      #pragma unroll
      for (int i = 0; i < 4; ++i)
        ZB[(mrow + jg*4 + i)*40 + col] = f2bf(acc[i] + bv);
    }
  }
  // phase 3: xhat = z@Wd + bd -> out
  {
    bf16x8 af = *(const bf16x8*)&ZB[(mrow + cl)*40 + jg*8];
    #pragma unroll
    for (int nt = 0; nt < 8; ++nt) {
      f32x4 acc = {0.f,0.f,0.f,0.f};
      bf16x8 bf = *(const bf16x8*)&Bds[(nt*16 + cl)*40 + jg*8];
      acc = __builtin_amdgcn_mfma_f32_16x16x32_bf16(af, bf, acc, 0, 0, 0);
      int col = nt*16 + cl;
      float bv = bd[col];
      #pragma unroll
      for (int i = 0; i < 4; ++i) {
        size_t grow = rbase + mrow + jg*4 + i;
        out[grow*DMF + col] = acc[i] + bv;
      }
    }
  }
}

extern "C" void kernel_launch(void* const* d_in, const int* in_sizes, int n_in,
                              void* d_out, int out_size, void* d_ws, size_t ws_size,
                              hipStream_t stream) {
  const float* xm   = (const float*)d_in[0];
  const float* xp   = (const float*)d_in[1];
  const int*   pidx = (const int*)d_in[2];
  const int*   midx = (const int*)d_in[3];
  const float* W1   = (const float*)d_in[4];
  const float* b1   = (const float*)d_in[5];
  const float* W2   = (const float*)d_in[6];
  const float* b2   = (const float*)d_in[7];
  const float* Wd   = (const float*)d_in[8];
  const float* bd   = (const float*)d_in[9];
  float* out = (float*)d_out;

  // ws layout (bytes):
  // deg[160000] dinv[160000] off[160256] cursor[160000]
  // inc[163840] bsum[160]+boff[164] (pad to 804480) csr[4000000]
  // W1t[32768] W2t[8192] Wdt[8192]
  // xw1[10240000] h[10240000] xw2[2560000] z[2560000]
  if (ws_size < (size_t)30453632) return;
  char* W = (char*)d_ws;
  int*    deg    = (int*)(W + 0);
  float*  dinv   = (float*)(W + 160000);
  int*    off    = (int*)(W + 320000);
  int*    cursor = (int*)(W + 480256);
  int*    inc    = (int*)(W + 640256);
  int*    bsum   = (int*)(W + 804096);
  int*    boff   = (int*)(W + 804256);
  int*    csr    = (int*)(W + 804480);
  ushort* W1t    = (ushort*)(W + 4804480);
  ushort* W2t    = (ushort*)(W + 4837248);
  ushort* Wdt    = (ushort*)(W + 4845440);
  ushort* xw1g   = (ushort*)(W + 4853632);
  ushort* hg     = (ushort*)(W + 15093632);
  ushort* xw2g   = (ushort*)(W + 25333632);
  ushort* zg     = (ushort*)(W + 27893632);

  k_prep      <<<1954,  256,  0, stream>>>(W1, W2, Wd, W1t, W2t, Wdt, out);
  k_deg_init  <<<157,   256,  0, stream>>>(deg);
  k_deg_count <<<1954,  256,  0, stream>>>(pidx, midx, deg);
  k_scan1     <<<40,    1024, 0, stream>>>(deg, dinv, inc, bsum);
  k_scan2     <<<1,     64,   0, stream>>>(bsum, boff, off);
  k_scan3     <<<40,    1024, 0, stream>>>(deg, inc, boff, off, cursor);
  k_fill      <<<1954,  256,  0, stream>>>(pidx, midx, off, cursor, csr);
  k_xw1m      <<<625,   256,  0, stream>>>(xm, xp, W1t, xw1g);
  k_gather1   <<<10000, 256,  0, stream>>>(off, csr, dinv, xw1g, b1, hg);
  k_xw2m      <<<625,   256,  0, stream>>>(hg, W2t, xw2g);
  k_gather2   <<<10000, 256,  0, stream>>>(off, csr, dinv, xw2g, b2, zg);
  k_decm      <<<625,   256,  0, stream>>>(zg, Wdt, bd, out);
  k_passm     <<<1250,  256,  0, stream>>>(xm, W1t, b1, W2t, b2, Wdt, bd, out);
}

// Round 8
// 170.145 us; speedup vs baseline: 4.7949x; 1.1935x over previous
//
#include <hip/hip_runtime.h>

#define NMN 100000
#define NPV 20000
#define DMF 128
#define DPF 64
#define NE  500000
#define HID 128
#define LAT 32
#define NACT (2*NPV)                  // 40000 edge-active nodes
#define OUT_PROV (NMN*DMF)            // 12,800,000
#define OUT_LOG  (OUT_PROV + NPV*DPF) // 14,080,000

typedef __attribute__((ext_vector_type(8))) short bf16x8;   // 8 bf16 = 4 VGPR
typedef __attribute__((ext_vector_type(4))) float f32x4;    // MFMA C/D

__device__ __forceinline__ ushort f2bf(float f) {
  unsigned u = __float_as_uint(f);
  u = (u + 0x7fffu + ((u >> 16) & 1u)) >> 16;   // RNE
  return (ushort)u;
}
__device__ __forceinline__ float bf2f(ushort h) {
  return __uint_as_float(((unsigned)h) << 16);
}
__device__ __forceinline__ unsigned pack2(float a, float b) {
  return (unsigned)f2bf(a) | ((unsigned)f2bf(b) << 16);
}
__device__ __forceinline__ float lo16(unsigned u) { return bf2f((ushort)(u & 0xffffu)); }
__device__ __forceinline__ float hi16(unsigned u) { return bf2f((ushort)(u >> 16)); }

// ---------------- degree ----------------
__global__ __launch_bounds__(256) void k_deg_init(int* deg) {
  int i = blockIdx.x*256 + threadIdx.x;
  if (i < NACT) deg[i] = 1;           // self-loop
}

__global__ __launch_bounds__(256) void k_deg_count(const int* __restrict__ pidx,
                                                   const int* __restrict__ midx,
                                                   int* __restrict__ deg) {
  int e = blockIdx.x*256 + threadIdx.x;
  if (e >= NE) return;
  atomicAdd(&deg[pidx[e]], 1);                 // dst = provider_idx (member node)
  int m = midx[e];
  if (m < NPV) atomicAdd(&deg[NPV + m], 1);    // dst = m+NM in-bounds only if m<NP
}

// ---------------- scan stage A: block-inclusive scan of (deg-1); fold dinv ----------------
__global__ __launch_bounds__(1024) void k_scan1(const int* __restrict__ deg,
                                                float* __restrict__ dinv,
                                                int* __restrict__ inc,
                                                int* __restrict__ bsum) {
  int tid = threadIdx.x;
  int i = blockIdx.x*1024 + tid;
  int val = 0;
  if (i < NACT) {
    int d = deg[i];
    val = d - 1;
    dinv[i] = rsqrtf((float)d);
  }
  int lane = tid & 63, wv = tid >> 6;
  int x = val;
  #pragma unroll
  for (int d = 1; d < 64; d <<= 1) {
    int o = __shfl_up(x, d);
    if (lane >= d) x += o;
  }
  __shared__ int wsums[16];
  if (lane == 63) wsums[wv] = x;
  __syncthreads();
  if (tid == 0) {
    int run = 0;
    #pragma unroll
    for (int j = 0; j < 16; ++j) { int t = wsums[j]; wsums[j] = run; run += t; }
  }
  __syncthreads();
  int incl = x + wsums[wv];
  inc[i] = incl;
  if (tid == 1023) bsum[blockIdx.x] = incl;
}

// ---------------- scan stage B: scan 40 block sums ----------------
__global__ __launch_bounds__(64) void k_scan2(const int* __restrict__ bsum,
                                              int* __restrict__ boff,
                                              int* __restrict__ off) {
  int t = threadIdx.x;
  int v = (t < 40) ? bsum[t] : 0;
  int x = v;
  #pragma unroll
  for (int d = 1; d < 64; d <<= 1) {
    int o = __shfl_up(x, d);
    if (t >= d) x += o;
  }
  if (t < 40) boff[t] = x - v;       // exclusive
  if (t == 39) off[NACT] = x;        // grand total
}

// ---------------- scan stage C: finalize off, zero cursor ----------------
__global__ __launch_bounds__(1024) void k_scan3(const int* __restrict__ deg,
                                                const int* __restrict__ inc,
                                                const int* __restrict__ boff,
                                                int* __restrict__ off,
                                                int* __restrict__ cursor) {
  int i = blockIdx.x*1024 + threadIdx.x;
  if (i < NACT) {
    int val = deg[i] - 1;
    off[i] = boff[blockIdx.x] + inc[i] - val;
    cursor[i] = 0;
  }
}

// ---------------- fill CSR (src lists per dst) ----------------
__global__ __launch_bounds__(256) void k_fill(const int* __restrict__ pidx,
                                              const int* __restrict__ midx,
                                              const int* __restrict__ off,
                                              int* __restrict__ cursor,
                                              int* __restrict__ csr) {
  int e = blockIdx.x*256 + threadIdx.x;
  if (e >= NE) return;
  int p = pidx[e], m = midx[e];
  int sa = NPV + (m < NPV ? m : NPV - 1);      // clamped provider-side src
  int pos = atomicAdd(&cursor[p], 1);
  csr[off[p] + pos] = sa;                      // edge into member node p
  if (m < NPV) {
    int da = NPV + m;
    int pos2 = atomicAdd(&cursor[da], 1);
    csr[off[da] + pos2] = p;                   // edge into provider node da
  }
}

// ---------------- weight prep (bf16 transposed) + zero edge logits ----------------
__global__ __launch_bounds__(256) void k_prep(const float* __restrict__ W1,
                                              const float* __restrict__ W2,
                                              const float* __restrict__ Wd,
                                              ushort* __restrict__ W1t,
                                              ushort* __restrict__ W2t,
                                              ushort* __restrict__ Wdt,
                                              float* __restrict__ out) {
  int i = blockIdx.x*256 + threadIdx.x;
  if (i < 16384) {                       // W1t[n*128+k] = W1[k][n]
    int n = i >> 7, k = i & 127;
    W1t[i] = f2bf(W1[k*HID + n]);
  } else if (i < 20480) {                // W2t[n*128+k] = W2[k][n]
    int j = i - 16384;
    int n = j >> 7, k = j & 127;
    W2t[j] = f2bf(W2[k*LAT + n]);
  } else if (i < 24576) {                // Wdt[n*32+k] = Wd[k][n]
    int j = i - 20480;
    int n = j >> 5, k = j & 31;
    Wdt[j] = f2bf(Wd[k*DMF + n]);
  }
  if (i < NE) out[OUT_LOG + i] = 0.f;
}

// ---------------- xw1 = x_active @ W1 (unscaled), MFMA, 64 rows/block ----------------
__global__ __launch_bounds__(256) void k_xw1m(const float* __restrict__ xm,
                                              const float* __restrict__ xp,
                                              const ushort* __restrict__ W1t,
                                              ushort* __restrict__ xw1) {
  __shared__ __align__(16) ushort As[64*136];
  __shared__ __align__(16) ushort Bs[128*136];
  int tid = threadIdx.x;
  int rbase = blockIdx.x * 64;
  for (int i = tid; i < 2048; i += 256) {
    int n = i >> 4, c = (i & 15) * 8;
    *(uint4*)&Bs[n*136 + c] = *(const uint4*)&W1t[n*128 + c];
  }
  for (int i = tid; i < 1024; i += 256) {
    int r = i >> 4, c = (i & 15) * 8;
    int a = rbase + r;
    float4 v0 = make_float4(0,0,0,0), v1 = v0;
    if (a < NPV) {
      v0 = *(const float4*)&xm[(size_t)a*DMF + c];
      v1 = *(const float4*)&xm[(size_t)a*DMF + c + 4];
    } else if (c < DPF) {
      int p = a - NPV;
      v0 = *(const float4*)&xp[(size_t)p*DPF + c];
      v1 = *(const float4*)&xp[(size_t)p*DPF + c + 4];
    }
    uint4 u;
    u.x = pack2(v0.x, v0.y); u.y = pack2(v0.z, v0.w);
    u.z = pack2(v1.x, v1.y); u.w = pack2(v1.z, v1.w);
    *(uint4*)&As[r*136 + c] = u;
  }
  __syncthreads();
  int w = tid >> 6, l = tid & 63;
  int mrow = w*16, cl = l & 15, jg = l >> 4;
  bf16x8 af[4];
  #pragma unroll
  for (int s = 0; s < 4; ++s)
    af[s] = *(const bf16x8*)&As[(mrow + cl)*136 + s*32 + jg*8];
  #pragma unroll
  for (int nt = 0; nt < 8; ++nt) {
    f32x4 acc = {0.f,0.f,0.f,0.f};
    #pragma unroll
    for (int s = 0; s < 4; ++s) {
      bf16x8 bf = *(const bf16x8*)&Bs[(nt*16 + cl)*136 + s*32 + jg*8];
      acc = __builtin_amdgcn_mfma_f32_16x16x32_bf16(af[s], bf, acc, 0, 0, 0);
    }
    int col = nt*16 + cl;
    #pragma unroll
    for (int i = 0; i < 4; ++i) {
      int grow = rbase + mrow + jg*4 + i;
      xw1[(size_t)grow*HID + col] = f2bf(acc[i]);
    }
  }
}

// ---------------- gather layer 1: round-5 semantics, manual 4x unroll (identical order) ----------------
__global__ __launch_bounds__(256) void k_gather1(const int* __restrict__ off,
                                                 const int* __restrict__ csr,
                                                 const float* __restrict__ dinv,
                                                 const ushort* __restrict__ xw1,
                                                 const float* __restrict__ b1,
                                                 ushort* __restrict__ h) {
  int tid = threadIdx.x;
  int dst = blockIdx.x*4 + (tid >> 6);   // exact: 10000 blocks * 4 waves
  int l = tid & 63;
  int s0 = off[dst], s1 = off[dst+1];
  float dd = dinv[dst];
  const unsigned* xb = (const unsigned*)xw1;
  unsigned su = xb[(size_t)dst*64 + l];  // self term (unscaled bf16)
  float ax = dd * lo16(su);
  float ay = dd * hi16(su);
  int i = s0;
  for (; i + 4 <= s1; i += 4) {
    int a0 = csr[i], a1 = csr[i+1], a2 = csr[i+2], a3 = csr[i+3];
    float d0 = dinv[a0], d1 = dinv[a1], d2 = dinv[a2], d3 = dinv[a3];
    unsigned u0 = xb[(size_t)a0*64 + l];
    unsigned u1 = xb[(size_t)a1*64 + l];
    unsigned u2 = xb[(size_t)a2*64 + l];
    unsigned u3 = xb[(size_t)a3*64 + l];
    ax += d0*lo16(u0); ay += d0*hi16(u0);
    ax += d1*lo16(u1); ay += d1*hi16(u1);
    ax += d2*lo16(u2); ay += d2*hi16(u2);
    ax += d3*lo16(u3); ay += d3*hi16(u3);
  }
  for (; i < s1; ++i) {
    int src = csr[i];
    float ds = dinv[src];
    unsigned u = xb[(size_t)src*64 + l];
    ax += ds * lo16(u);
    ay += ds * hi16(u);
  }
  float2 b = ((const float2*)b1)[l];
  float rx = dd*ax + b.x; rx = rx > 0.f ? rx : 0.f;
  float ry = dd*ay + b.y; ry = ry > 0.f ? ry : 0.f;
  ((unsigned*)h)[(size_t)dst*64 + l] = pack2(rx, ry);
}

// ---------------- xw2 = h @ W2 (unscaled), MFMA ----------------
__global__ __launch_bounds__(256) void k_xw2m(const ushort* __restrict__ hg,
                                              const ushort* __restrict__ W2t,
                                              ushort* __restrict__ xw2) {
  __shared__ __align__(16) ushort As[64*136];
  __shared__ __align__(16) ushort Bs[32*136];
  int tid = threadIdx.x;
  int rbase = blockIdx.x * 64;
  for (int i = tid; i < 512; i += 256) {
    int n = i >> 4, c = (i & 15) * 8;
    *(uint4*)&Bs[n*136 + c] = *(const uint4*)&W2t[n*128 + c];
  }
  for (int i = tid; i < 1024; i += 256) {
    int r = i >> 4, c = (i & 15) * 8;
    *(uint4*)&As[r*136 + c] = *(const uint4*)&hg[(size_t)(rbase + r)*HID + c];
  }
  __syncthreads();
  int w = tid >> 6, l = tid & 63;
  int mrow = w*16, cl = l & 15, jg = l >> 4;
  bf16x8 af[4];
  #pragma unroll
  for (int s = 0; s < 4; ++s)
    af[s] = *(const bf16x8*)&As[(mrow + cl)*136 + s*32 + jg*8];
  #pragma unroll
  for (int nt = 0; nt < 2; ++nt) {
    f32x4 acc = {0.f,0.f,0.f,0.f};
    #pragma unroll
    for (int s = 0; s < 4; ++s) {
      bf16x8 bf = *(const bf16x8*)&Bs[(nt*16 + cl)*136 + s*32 + jg*8];
      acc = __builtin_amdgcn_mfma_f32_16x16x32_bf16(af[s], bf, acc, 0, 0, 0);
    }
    int col = nt*16 + cl;
    #pragma unroll
    for (int i = 0; i < 4; ++i) {
      int grow = rbase + mrow + jg*4 + i;
      xw2[(size_t)grow*LAT + col] = f2bf(acc[i]);
    }
  }
}

// ---------------- gather layer 2: round-5 semantics, manual 4x unroll per half-stream ----------------
__global__ __launch_bounds__(256) void k_gather2(const int* __restrict__ off,
                                                 const int* __restrict__ csr,
                                                 const float* __restrict__ dinv,
                                                 const ushort* __restrict__ xw2,
                                                 const float* __restrict__ b2,
                                                 ushort* __restrict__ z) {
  int tid = threadIdx.x;
  int dst = blockIdx.x*4 + (tid >> 6);   // one wave per dst, 10000 blocks
  int l = tid & 63;
  int half = l >> 5, c = l & 31;
  int s0 = off[dst], s1 = off[dst+1];
  float dd = dinv[dst];
  float acc = 0.f;
  int i = s0 + half;
  for (; i + 6 < s1; i += 8) {           // 4 elems of this half-stream: i,i+2,i+4,i+6
    int a0 = csr[i], a1 = csr[i+2], a2 = csr[i+4], a3 = csr[i+6];
    float d0 = dinv[a0], d1 = dinv[a1], d2 = dinv[a2], d3 = dinv[a3];
    float x0 = bf2f(xw2[(size_t)a0*LAT + c]);
    float x1 = bf2f(xw2[(size_t)a1*LAT + c]);
    float x2 = bf2f(xw2[(size_t)a2*LAT + c]);
    float x3 = bf2f(xw2[(size_t)a3*LAT + c]);
    acc += d0*x0; acc += d1*x1; acc += d2*x2; acc += d3*x3;
  }
  for (; i < s1; i += 2) {
    int src = csr[i];
    acc += dinv[src] * bf2f(xw2[(size_t)src*LAT + c]);
  }
  acc += __shfl_xor(acc, 32);
  float res = dd*(acc + dd*bf2f(xw2[(size_t)dst*LAT + c])) + b2[c];
  if (half == 0) z[(size_t)dst*LAT + c] = f2bf(res);
}

// ---------------- decode active, MFMA (K=32, one k-step) ----------------
__global__ __launch_bounds__(256) void k_decm(const ushort* __restrict__ zg,
                                              const ushort* __restrict__ Wdt,
                                              const float* __restrict__ bd,
                                              float* __restrict__ out) {
  __shared__ __align__(16) ushort As[64*40];
  __shared__ __align__(16) ushort Bs[128*40];
  int tid = threadIdx.x;
  int rbase = blockIdx.x * 64;
  for (int i = tid; i < 512; i += 256) {
    int n = i >> 2, c = (i & 3) * 8;
    *(uint4*)&Bs[n*40 + c] = *(const uint4*)&Wdt[n*32 + c];
  }
  {
    int r = tid >> 2, c = (tid & 3) * 8;   // 256 chunks exactly
    *(uint4*)&As[r*40 + c] = *(const uint4*)&zg[(size_t)(rbase + r)*LAT + c];
  }
  __syncthreads();
  int w = tid >> 6, l = tid & 63;
  int mrow = w*16, cl = l & 15, jg = l >> 4;
  bf16x8 af = *(const bf16x8*)&As[(mrow + cl)*40 + jg*8];
  #pragma unroll
  for (int nt = 0; nt < 8; ++nt) {
    f32x4 acc = {0.f,0.f,0.f,0.f};
    bf16x8 bf = *(const bf16x8*)&Bs[(nt*16 + cl)*40 + jg*8];
    acc = __builtin_amdgcn_mfma_f32_16x16x32_bf16(af, bf, acc, 0, 0, 0);
    int col = nt*16 + cl;
    float bv = bd[col];
    #pragma unroll
    for (int i = 0; i < 4; ++i) {
      int grow = rbase + mrow + jg*4 + i;
      float v = acc[i] + bv;
      if (grow < NPV) out[(size_t)grow*DMF + col] = v;
      else if (col < DPF) out[OUT_PROV + (size_t)(grow - NPV)*DPF + col] = v;
    }
  }
}

// ---------------- fused passive MLP, MFMA, 64 rows/block ----------------
__global__ __launch_bounds__(256) void k_passm(const float* __restrict__ xm,
                                               const ushort* __restrict__ W1t,
                                               const float* __restrict__ b1,
                                               const ushort* __restrict__ W2t,
                                               const float* __restrict__ b2,
                                               const ushort* __restrict__ Wdt,
                                               const float* __restrict__ bd,
                                               float* __restrict__ out) {
  __shared__ __align__(16) ushort XH[64*136];   // x, overwritten by h (wave-private rows)
  __shared__ __align__(16) ushort ZB[64*40];
  __shared__ __align__(16) ushort B1s[128*136];
  __shared__ __align__(16) ushort B2s[32*136];
  __shared__ __align__(16) ushort Bds[128*40];
  int tid = threadIdx.x;
  int rbase = NPV + blockIdx.x * 64;            // member rows 20000..99999
  for (int i = tid; i < 2048; i += 256) {
    int n = i >> 4, c = (i & 15) * 8;
    *(uint4*)&B1s[n*136 + c] = *(const uint4*)&W1t[n*128 + c];
  }
  for (int i = tid; i < 512; i += 256) {
    int n = i >> 4, c = (i & 15) * 8;
    *(uint4*)&B2s[n*136 + c] = *(const uint4*)&W2t[n*128 + c];
  }
  for (int i = tid; i < 512; i += 256) {
    int n = i >> 2, c = (i & 3) * 8;
    *(uint4*)&Bds[n*40 + c] = *(const uint4*)&Wdt[n*32 + c];
  }
  for (int i = tid; i < 1024; i += 256) {
    int r = i >> 4, c = (i & 15) * 8;
    float4 v0 = *(const float4*)&xm[(size_t)(rbase + r)*DMF + c];
    float4 v1 = *(const float4*)&xm[(size_t)(rbase + r)*DMF + c + 4];
    uint4 u;
    u.x = pack2(v0.x, v0.y); u.y = pack2(v0.z, v0.w);
    u.z = pack2(v1.x, v1.y); u.w = pack2(v1.z, v1.w);
    *(uint4*)&XH[r*136 + c] = u;
  }
  __syncthreads();                              // the ONLY barrier
  int w = tid >> 6, l = tid & 63;
  int mrow = w*16, cl = l & 15, jg = l >> 4;
  // phase 1: h = relu(x@W1 + b1) -> XH in place (rows wave-private; A preloaded)
  {
    bf16x8 af[4];
    #pragma unroll
    for (int s = 0; s < 4; ++s)
      af[s] = *(const bf16x8*)&XH[(mrow + cl)*136 + s*32 + jg*8];
    #pragma unroll
    for (int nt = 0; nt < 8; ++nt) {
      f32x4 acc = {0.f,0.f,0.f,0.f};
      #pragma unroll
      for (int s = 0; s < 4; ++s) {
        bf16x8 bf = *(const bf16x8*)&B1s[(nt*16 + cl)*136 + s*32 + jg*8];
        acc = __builtin_amdgcn_mfma_f32_16x16x32_bf16(af[s], bf, acc, 0, 0, 0);
      }
      int col = nt*16 + cl;
      float bv = b1[col];
      #pragma unroll
      for (int i = 0; i < 4; ++i) {
        float v = acc[i] + bv;
        v = v > 0.f ? v : 0.f;
        XH[(mrow + jg*4 + i)*136 + col] = f2bf(v);
      }
    }
  }
  // phase 2: z = h@W2 + b2 -> ZB
  {
    bf16x8 af[4];
    #pragma unroll
    for (int s = 0; s < 4; ++s)
      af[s] = *(const bf16x8*)&XH[(mrow + cl)*136 + s*32 + jg*8];
    #pragma unroll
    for (int nt = 0; nt < 2; ++nt) {
      f32x4 acc = {0.f,0.f,0.f,0.f};
      #pragma unroll
      for (int s = 0; s < 4; ++s) {
        bf16x8 bf = *(const bf16x8*)&B2s[(nt*16 + cl)*136 + s*32 + jg*8];
        acc = __builtin_amdgcn_mfma_f32_16x16x32_bf16(af[s], bf, acc, 0, 0, 0);
      }
      int col = nt*16 + cl;
      float bv = b2[col];
      #pragma unroll
      for (int i = 0; i < 4; ++i)
        ZB[(mrow + jg*4 + i)*40 + col] = f2bf(acc[i] + bv);
    }
  }
  // phase 3: xhat = z@Wd + bd -> out
  {
    bf16x8 af = *(const bf16x8*)&ZB[(mrow + cl)*40 + jg*8];
    #pragma unroll
    for (int nt = 0; nt < 8; ++nt) {
      f32x4 acc = {0.f,0.f,0.f,0.f};
      bf16x8 bf = *(const bf16x8*)&Bds[(nt*16 + cl)*40 + jg*8];
      acc = __builtin_amdgcn_mfma_f32_16x16x32_bf16(af, bf, acc, 0, 0, 0);
      int col = nt*16 + cl;
      float bv = bd[col];
      #pragma unroll
      for (int i = 0; i < 4; ++i) {
        size_t grow = rbase + mrow + jg*4 + i;
        out[grow*DMF + col] = acc[i] + bv;
      }
    }
  }
}

extern "C" void kernel_launch(void* const* d_in, const int* in_sizes, int n_in,
                              void* d_out, int out_size, void* d_ws, size_t ws_size,
                              hipStream_t stream) {
  const float* xm   = (const float*)d_in[0];
  const float* xp   = (const float*)d_in[1];
  const int*   pidx = (const int*)d_in[2];
  const int*   midx = (const int*)d_in[3];
  const float* W1   = (const float*)d_in[4];
  const float* b1   = (const float*)d_in[5];
  const float* W2   = (const float*)d_in[6];
  const float* b2   = (const float*)d_in[7];
  const float* Wd   = (const float*)d_in[8];
  const float* bd   = (const float*)d_in[9];
  float* out = (float*)d_out;

  // ws layout (bytes):
  // deg[160000] dinv[160000] off[160256] cursor[160000]
  // inc[163840] bsum[160]+boff[164] (pad to 804480) csr[4000000]
  // W1t[32768] W2t[8192] Wdt[8192]
  // xw1[10240000] h[10240000] xw2[2560000] z[2560000]
  if (ws_size < (size_t)30453632) return;
  char* W = (char*)d_ws;
  int*    deg    = (int*)(W + 0);
  float*  dinv   = (float*)(W + 160000);
  int*    off    = (int*)(W + 320000);
  int*    cursor = (int*)(W + 480256);
  int*    inc    = (int*)(W + 640256);
  int*    bsum   = (int*)(W + 804096);
  int*    boff   = (int*)(W + 804256);
  int*    csr    = (int*)(W + 804480);
  ushort* W1t    = (ushort*)(W + 4804480);
  ushort* W2t    = (ushort*)(W + 4837248);
  ushort* Wdt    = (ushort*)(W + 4845440);
  ushort* xw1g   = (ushort*)(W + 4853632);
  ushort* hg     = (ushort*)(W + 15093632);
  ushort* xw2g   = (ushort*)(W + 25333632);
  ushort* zg     = (ushort*)(W + 27893632);

  k_prep      <<<1954,  256,  0, stream>>>(W1, W2, Wd, W1t, W2t, Wdt, out);
  k_deg_init  <<<157,   256,  0, stream>>>(deg);
  k_deg_count <<<1954,  256,  0, stream>>>(pidx, midx, deg);
  k_scan1     <<<40,    1024, 0, stream>>>(deg, dinv, inc, bsum);
  k_scan2     <<<1,     64,   0, stream>>>(bsum, boff, off);
  k_scan3     <<<40,    1024, 0, stream>>>(deg, inc, boff, off, cursor);
  k_fill      <<<1954,  256,  0, stream>>>(pidx, midx, off, cursor, csr);
  k_xw1m      <<<625,   256,  0, stream>>>(xm, xp, W1t, xw1g);
  k_gather1   <<<10000, 256,  0, stream>>>(off, csr, dinv, xw1g, b1, hg);
  k_xw2m      <<<625,   256,  0, stream>>>(hg, W2t, xw2g);
  k_gather2   <<<10000, 256,  0, stream>>>(off, csr, dinv, xw2g, b2, zg);
  k_decm      <<<625,   256,  0, stream>>>(zg, Wdt, bd, out);
  k_passm     <<<1250,  256,  0, stream>>>(xm, W1t, b1, W2t, b2, Wdt, bd, out);
}

// Round 9
// 161.406 us; speedup vs baseline: 5.0546x; 1.0541x over previous
//
#include <hip/hip_runtime.h>

#define NMN 100000
#define NPV 20000
#define DMF 128
#define DPF 64
#define NE  500000
#define HID 128
#define LAT 32
#define NACT (2*NPV)                  // 40000 edge-active nodes
#define OUT_PROV (NMN*DMF)            // 12,800,000
#define OUT_LOG  (OUT_PROV + NPV*DPF) // 14,080,000

typedef __attribute__((ext_vector_type(8))) short bf16x8;   // 8 bf16 = 4 VGPR
typedef __attribute__((ext_vector_type(4))) float f32x4;    // MFMA C/D

__device__ __forceinline__ ushort f2bf(float f) {
  unsigned u = __float_as_uint(f);
  u = (u + 0x7fffu + ((u >> 16) & 1u)) >> 16;   // RNE
  return (ushort)u;
}
__device__ __forceinline__ float bf2f(ushort h) {
  return __uint_as_float(((unsigned)h) << 16);
}
__device__ __forceinline__ unsigned pack2(float a, float b) {
  return (unsigned)f2bf(a) | ((unsigned)f2bf(b) << 16);
}
__device__ __forceinline__ float lo16(unsigned u) { return bf2f((ushort)(u & 0xffffu)); }
__device__ __forceinline__ float hi16(unsigned u) { return bf2f((ushort)(u >> 16)); }

// ---------------- degree count ----------------
__global__ __launch_bounds__(256) void k_deg_count(const int* __restrict__ pidx,
                                                   const int* __restrict__ midx,
                                                   int* __restrict__ deg) {
  int e = blockIdx.x*256 + threadIdx.x;
  if (e >= NE) return;
  atomicAdd(&deg[pidx[e]], 1);                 // dst = provider_idx (member node)
  int m = midx[e];
  if (m < NPV) atomicAdd(&deg[NPV + m], 1);    // dst = m+NM in-bounds only if m<NP
}

// ---------------- scan stage A: block-inclusive scan of (deg-1); fold dinv ----------------
__global__ __launch_bounds__(1024) void k_scan1(const int* __restrict__ deg,
                                                float* __restrict__ dinv,
                                                int* __restrict__ inc,
                                                int* __restrict__ bsum) {
  int tid = threadIdx.x;
  int i = blockIdx.x*1024 + tid;
  int val = 0;
  if (i < NACT) {
    int d = deg[i];
    val = d - 1;
    dinv[i] = rsqrtf((float)d);
  }
  int lane = tid & 63, wv = tid >> 6;
  int x = val;
  #pragma unroll
  for (int d = 1; d < 64; d <<= 1) {
    int o = __shfl_up(x, d);
    if (lane >= d) x += o;
  }
  __shared__ int wsums[16];
  if (lane == 63) wsums[wv] = x;
  __syncthreads();
  if (tid == 0) {
    int run = 0;
    #pragma unroll
    for (int j = 0; j < 16; ++j) { int t = wsums[j]; wsums[j] = run; run += t; }
  }
  __syncthreads();
  int incl = x + wsums[wv];
  inc[i] = incl;
  if (tid == 1023) bsum[blockIdx.x] = incl;
}

// ---------------- scan stage C: finalize off (own 40-prefix), zero cursor ----------------
__global__ __launch_bounds__(1024) void k_scan3(const int* __restrict__ deg,
                                                const int* __restrict__ inc,
                                                const int* __restrict__ bsum,
                                                int* __restrict__ off,
                                                int* __restrict__ cursor) {
  int b = blockIdx.x;
  int boffb = 0;
  #pragma unroll 8
  for (int k = 0; k < 40; ++k) boffb += (k < b) ? bsum[k] : 0;   // L1-broadcast
  int i = b*1024 + threadIdx.x;
  if (i < NACT) {
    int val = deg[i] - 1;
    off[i] = boffb + inc[i] - val;
    cursor[i] = 0;
  }
  if (i == NACT) off[NACT] = boffb + bsum[39];   // only in block 39: grand total
}

// ---------------- fill CSR (src lists per dst) ----------------
__global__ __launch_bounds__(256) void k_fill(const int* __restrict__ pidx,
                                              const int* __restrict__ midx,
                                              const int* __restrict__ off,
                                              int* __restrict__ cursor,
                                              int* __restrict__ csr) {
  int e = blockIdx.x*256 + threadIdx.x;
  if (e >= NE) return;
  int p = pidx[e], m = midx[e];
  int sa = NPV + (m < NPV ? m : NPV - 1);      // clamped provider-side src
  int pos = atomicAdd(&cursor[p], 1);
  csr[off[p] + pos] = sa;                      // edge into member node p
  if (m < NPV) {
    int da = NPV + m;
    int pos2 = atomicAdd(&cursor[da], 1);
    csr[off[da] + pos2] = p;                   // edge into provider node da
  }
}

// ---------------- weight prep (bf16 transposed) + zero logits + deg init ----------------
__global__ __launch_bounds__(256) void k_prep(const float* __restrict__ W1,
                                              const float* __restrict__ W2,
                                              const float* __restrict__ Wd,
                                              ushort* __restrict__ W1t,
                                              ushort* __restrict__ W2t,
                                              ushort* __restrict__ Wdt,
                                              int* __restrict__ deg,
                                              float* __restrict__ out) {
  int i = blockIdx.x*256 + threadIdx.x;
  if (i < 16384) {                       // W1t[n*128+k] = W1[k][n]
    int n = i >> 7, k = i & 127;
    W1t[i] = f2bf(W1[k*HID + n]);
  } else if (i < 20480) {                // W2t[n*128+k] = W2[k][n]
    int j = i - 16384;
    int n = j >> 7, k = j & 127;
    W2t[j] = f2bf(W2[k*LAT + n]);
  } else if (i < 24576) {                // Wdt[n*32+k] = Wd[k][n]
    int j = i - 20480;
    int n = j >> 5, k = j & 31;
    Wdt[j] = f2bf(Wd[k*DMF + n]);
  }
  if (i < NACT) deg[i] = 1;              // self-loop (independent write; safe to fuse)
  if (i < NE) out[OUT_LOG + i] = 0.f;
}

// ---------------- xw1 = x_active @ W1 (unscaled), MFMA, 64 rows/block ----------------
__global__ __launch_bounds__(256) void k_xw1m(const float* __restrict__ xm,
                                              const float* __restrict__ xp,
                                              const ushort* __restrict__ W1t,
                                              ushort* __restrict__ xw1) {
  __shared__ __align__(16) ushort As[64*136];
  __shared__ __align__(16) ushort Bs[128*136];
  int tid = threadIdx.x;
  int rbase = blockIdx.x * 64;
  for (int i = tid; i < 2048; i += 256) {
    int n = i >> 4, c = (i & 15) * 8;
    *(uint4*)&Bs[n*136 + c] = *(const uint4*)&W1t[n*128 + c];
  }
  for (int i = tid; i < 1024; i += 256) {
    int r = i >> 4, c = (i & 15) * 8;
    int a = rbase + r;
    float4 v0 = make_float4(0,0,0,0), v1 = v0;
    if (a < NPV) {
      v0 = *(const float4*)&xm[(size_t)a*DMF + c];
      v1 = *(const float4*)&xm[(size_t)a*DMF + c + 4];
    } else if (c < DPF) {
      int p = a - NPV;
      v0 = *(const float4*)&xp[(size_t)p*DPF + c];
      v1 = *(const float4*)&xp[(size_t)p*DPF + c + 4];
    }
    uint4 u;
    u.x = pack2(v0.x, v0.y); u.y = pack2(v0.z, v0.w);
    u.z = pack2(v1.x, v1.y); u.w = pack2(v1.z, v1.w);
    *(uint4*)&As[r*136 + c] = u;
  }
  __syncthreads();
  int w = tid >> 6, l = tid & 63;
  int mrow = w*16, cl = l & 15, jg = l >> 4;
  bf16x8 af[4];
  #pragma unroll
  for (int s = 0; s < 4; ++s)
    af[s] = *(const bf16x8*)&As[(mrow + cl)*136 + s*32 + jg*8];
  #pragma unroll
  for (int nt = 0; nt < 8; ++nt) {
    f32x4 acc = {0.f,0.f,0.f,0.f};
    #pragma unroll
    for (int s = 0; s < 4; ++s) {
      bf16x8 bf = *(const bf16x8*)&Bs[(nt*16 + cl)*136 + s*32 + jg*8];
      acc = __builtin_amdgcn_mfma_f32_16x16x32_bf16(af[s], bf, acc, 0, 0, 0);
    }
    int col = nt*16 + cl;
    #pragma unroll
    for (int i = 0; i < 4; ++i) {
      int grow = rbase + mrow + jg*4 + i;
      xw1[(size_t)grow*HID + col] = f2bf(acc[i]);
    }
  }
}

// ---------------- gather layer 1: TWO dsts per wave, unroll-4 each (order preserved) ----------------
__global__ __launch_bounds__(256) void k_gather1(const int* __restrict__ off,
                                                 const int* __restrict__ csr,
                                                 const float* __restrict__ dinv,
                                                 const ushort* __restrict__ xw1,
                                                 const float* __restrict__ b1,
                                                 ushort* __restrict__ h) {
  int tid = threadIdx.x;
  int wid = blockIdx.x*4 + (tid >> 6);   // 5000 blocks * 4 waves = 20000 wave-ids
  int dA = wid*2, dB = wid*2 + 1;
  int l = tid & 63;
  int ia = off[dA], aE = off[dA+1];
  int jb = off[dB], bE = off[dB+1];
  float ddA = dinv[dA], ddB = dinv[dB];
  const unsigned* xb = (const unsigned*)xw1;
  unsigned suA = xb[(size_t)dA*64 + l];
  unsigned suB = xb[(size_t)dB*64 + l];
  float axA = ddA*lo16(suA), ayA = ddA*hi16(suA);
  float axB = ddB*lo16(suB), ayB = ddB*hi16(suB);
  // dual main loop: 4 edges from each list interleaved -> 8 row-loads in flight
  for (; ia + 4 <= aE && jb + 4 <= bE; ia += 4, jb += 4) {
    int a0 = csr[ia], a1 = csr[ia+1], a2 = csr[ia+2], a3 = csr[ia+3];
    int b0 = csr[jb], b1i = csr[jb+1], b2 = csr[jb+2], b3 = csr[jb+3];
    float dA0 = dinv[a0], dA1 = dinv[a1], dA2 = dinv[a2], dA3 = dinv[a3];
    float dB0 = dinv[b0], dB1 = dinv[b1i], dB2 = dinv[b2], dB3 = dinv[b3];
    unsigned uA0 = xb[(size_t)a0*64 + l], uA1 = xb[(size_t)a1*64 + l];
    unsigned uA2 = xb[(size_t)a2*64 + l], uA3 = xb[(size_t)a3*64 + l];
    unsigned uB0 = xb[(size_t)b0*64 + l], uB1 = xb[(size_t)b1i*64 + l];
    unsigned uB2 = xb[(size_t)b2*64 + l], uB3 = xb[(size_t)b3*64 + l];
    axA += dA0*lo16(uA0); ayA += dA0*hi16(uA0);
    axA += dA1*lo16(uA1); ayA += dA1*hi16(uA1);
    axA += dA2*lo16(uA2); ayA += dA2*hi16(uA2);
    axA += dA3*lo16(uA3); ayA += dA3*hi16(uA3);
    axB += dB0*lo16(uB0); ayB += dB0*hi16(uB0);
    axB += dB1*lo16(uB1); ayB += dB1*hi16(uB1);
    axB += dB2*lo16(uB2); ayB += dB2*hi16(uB2);
    axB += dB3*lo16(uB3); ayB += dB3*hi16(uB3);
  }
  // finish list A (r8 tail structure: unroll-4 then scalar)
  for (; ia + 4 <= aE; ia += 4) {
    int a0 = csr[ia], a1 = csr[ia+1], a2 = csr[ia+2], a3 = csr[ia+3];
    float d0 = dinv[a0], d1 = dinv[a1], d2 = dinv[a2], d3 = dinv[a3];
    unsigned u0 = xb[(size_t)a0*64 + l], u1 = xb[(size_t)a1*64 + l];
    unsigned u2 = xb[(size_t)a2*64 + l], u3 = xb[(size_t)a3*64 + l];
    axA += d0*lo16(u0); ayA += d0*hi16(u0);
    axA += d1*lo16(u1); ayA += d1*hi16(u1);
    axA += d2*lo16(u2); ayA += d2*hi16(u2);
    axA += d3*lo16(u3); ayA += d3*hi16(u3);
  }
  for (; ia < aE; ++ia) {
    int src = csr[ia];
    float ds = dinv[src];
    unsigned u = xb[(size_t)src*64 + l];
    axA += ds*lo16(u); ayA += ds*hi16(u);
  }
  // finish list B
  for (; jb + 4 <= bE; jb += 4) {
    int a0 = csr[jb], a1 = csr[jb+1], a2 = csr[jb+2], a3 = csr[jb+3];
    float d0 = dinv[a0], d1 = dinv[a1], d2 = dinv[a2], d3 = dinv[a3];
    unsigned u0 = xb[(size_t)a0*64 + l], u1 = xb[(size_t)a1*64 + l];
    unsigned u2 = xb[(size_t)a2*64 + l], u3 = xb[(size_t)a3*64 + l];
    axB += d0*lo16(u0); ayB += d0*hi16(u0);
    axB += d1*lo16(u1); ayB += d1*hi16(u1);
    axB += d2*lo16(u2); ayB += d2*hi16(u2);
    axB += d3*lo16(u3); ayB += d3*hi16(u3);
  }
  for (; jb < bE; ++jb) {
    int src = csr[jb];
    float ds = dinv[src];
    unsigned u = xb[(size_t)src*64 + l];
    axB += ds*lo16(u); ayB += ds*hi16(u);
  }
  float2 b = ((const float2*)b1)[l];
  float rxA = ddA*axA + b.x; rxA = rxA > 0.f ? rxA : 0.f;
  float ryA = ddA*ayA + b.y; ryA = ryA > 0.f ? ryA : 0.f;
  float rxB = ddB*axB + b.x; rxB = rxB > 0.f ? rxB : 0.f;
  float ryB = ddB*ayB + b.y; ryB = ryB > 0.f ? ryB : 0.f;
  ((unsigned*)h)[(size_t)dA*64 + l] = pack2(rxA, ryA);
  ((unsigned*)h)[(size_t)dB*64 + l] = pack2(rxB, ryB);
}

// ---------------- xw2 = h @ W2 (unscaled), MFMA ----------------
__global__ __launch_bounds__(256) void k_xw2m(const ushort* __restrict__ hg,
                                              const ushort* __restrict__ W2t,
                                              ushort* __restrict__ xw2) {
  __shared__ __align__(16) ushort As[64*136];
  __shared__ __align__(16) ushort Bs[32*136];
  int tid = threadIdx.x;
  int rbase = blockIdx.x * 64;
  for (int i = tid; i < 512; i += 256) {
    int n = i >> 4, c = (i & 15) * 8;
    *(uint4*)&Bs[n*136 + c] = *(const uint4*)&W2t[n*128 + c];
  }
  for (int i = tid; i < 1024; i += 256) {
    int r = i >> 4, c = (i & 15) * 8;
    *(uint4*)&As[r*136 + c] = *(const uint4*)&hg[(size_t)(rbase + r)*HID + c];
  }
  __syncthreads();
  int w = tid >> 6, l = tid & 63;
  int mrow = w*16, cl = l & 15, jg = l >> 4;
  bf16x8 af[4];
  #pragma unroll
  for (int s = 0; s < 4; ++s)
    af[s] = *(const bf16x8*)&As[(mrow + cl)*136 + s*32 + jg*8];
  #pragma unroll
  for (int nt = 0; nt < 2; ++nt) {
    f32x4 acc = {0.f,0.f,0.f,0.f};
    #pragma unroll
    for (int s = 0; s < 4; ++s) {
      bf16x8 bf = *(const bf16x8*)&Bs[(nt*16 + cl)*136 + s*32 + jg*8];
      acc = __builtin_amdgcn_mfma_f32_16x16x32_bf16(af[s], bf, acc, 0, 0, 0);
    }
    int col = nt*16 + cl;
    #pragma unroll
    for (int i = 0; i < 4; ++i) {
      int grow = rbase + mrow + jg*4 + i;
      xw2[(size_t)grow*LAT + col] = f2bf(acc[i]);
    }
  }
}

// ---------------- gather layer 2: TWO dsts per wave, half-stream unroll-4 each ----------------
__global__ __launch_bounds__(256) void k_gather2(const int* __restrict__ off,
                                                 const int* __restrict__ csr,
                                                 const float* __restrict__ dinv,
                                                 const ushort* __restrict__ xw2,
                                                 const float* __restrict__ b2,
                                                 ushort* __restrict__ z) {
  int tid = threadIdx.x;
  int wid = blockIdx.x*4 + (tid >> 6);   // 5000 blocks * 4 waves
  int dA = wid*2, dB = wid*2 + 1;
  int l = tid & 63;
  int half = l >> 5, c = l & 31;
  int a0s = off[dA], aE = off[dA+1];
  int b0s = off[dB], bE = off[dB+1];
  float ddA = dinv[dA], ddB = dinv[dB];
  float accA = 0.f, accB = 0.f;
  int i = a0s + half, j = b0s + half;
  // dual main loop: 4 elems of each half-stream from each list
  for (; i + 6 < aE && j + 6 < bE; i += 8, j += 8) {
    int a0 = csr[i], a1 = csr[i+2], a2 = csr[i+4], a3 = csr[i+6];
    int b0 = csr[j], b1i = csr[j+2], b2 = csr[j+4], b3 = csr[j+6];
    float dA0 = dinv[a0], dA1 = dinv[a1], dA2 = dinv[a2], dA3 = dinv[a3];
    float dB0 = dinv[b0], dB1 = dinv[b1i], dB2 = dinv[b2], dB3 = dinv[b3];
    float xA0 = bf2f(xw2[(size_t)a0*LAT + c]);
    float xA1 = bf2f(xw2[(size_t)a1*LAT + c]);
    float xA2 = bf2f(xw2[(size_t)a2*LAT + c]);
    float xA3 = bf2f(xw2[(size_t)a3*LAT + c]);
    float xB0 = bf2f(xw2[(size_t)b0*LAT + c]);
    float xB1 = bf2f(xw2[(size_t)b1i*LAT + c]);
    float xB2 = bf2f(xw2[(size_t)b2*LAT + c]);
    float xB3 = bf2f(xw2[(size_t)b3*LAT + c]);
    accA += dA0*xA0; accA += dA1*xA1; accA += dA2*xA2; accA += dA3*xA3;
    accB += dB0*xB0; accB += dB1*xB1; accB += dB2*xB2; accB += dB3*xB3;
  }
  // finish A
  for (; i + 6 < aE; i += 8) {
    int a0 = csr[i], a1 = csr[i+2], a2 = csr[i+4], a3 = csr[i+6];
    float d0 = dinv[a0], d1 = dinv[a1], d2 = dinv[a2], d3 = dinv[a3];
    float x0 = bf2f(xw2[(size_t)a0*LAT + c]);
    float x1 = bf2f(xw2[(size_t)a1*LAT + c]);
    float x2 = bf2f(xw2[(size_t)a2*LAT + c]);
    float x3 = bf2f(xw2[(size_t)a3*LAT + c]);
    accA += d0*x0; accA += d1*x1; accA += d2*x2; accA += d3*x3;
  }
  for (; i < aE; i += 2) {
    int src = csr[i];
    accA += dinv[src] * bf2f(xw2[(size_t)src*LAT + c]);
  }
  // finish B
  for (; j + 6 < bE; j += 8) {
    int a0 = csr[j], a1 = csr[j+2], a2 = csr[j+4], a3 = csr[j+6];
    float d0 = dinv[a0], d1 = dinv[a1], d2 = dinv[a2], d3 = dinv[a3];
    float x0 = bf2f(xw2[(size_t)a0*LAT + c]);
    float x1 = bf2f(xw2[(size_t)a1*LAT + c]);
    float x2 = bf2f(xw2[(size_t)a2*LAT + c]);
    float x3 = bf2f(xw2[(size_t)a3*LAT + c]);
    accB += d0*x0; accB += d1*x1; accB += d2*x2; accB += d3*x3;
  }
  for (; j < bE; j += 2) {
    int src = csr[j];
    accB += dinv[src] * bf2f(xw2[(size_t)src*LAT + c]);
  }
  accA += __shfl_xor(accA, 32);
  accB += __shfl_xor(accB, 32);
  float resA = ddA*(accA + ddA*bf2f(xw2[(size_t)dA*LAT + c])) + b2[c];
  float resB = ddB*(accB + ddB*bf2f(xw2[(size_t)dB*LAT + c])) + b2[c];
  if (half == 0) {
    z[(size_t)dA*LAT + c] = f2bf(resA);
    z[(size_t)dB*LAT + c] = f2bf(resB);
  }
}

// ---------------- decode active, MFMA (K=32, one k-step) ----------------
__global__ __launch_bounds__(256) void k_decm(const ushort* __restrict__ zg,
                                              const ushort* __restrict__ Wdt,
                                              const float* __restrict__ bd,
                                              float* __restrict__ out) {
  __shared__ __align__(16) ushort As[64*40];
  __shared__ __align__(16) ushort Bs[128*40];
  int tid = threadIdx.x;
  int rbase = blockIdx.x * 64;
  for (int i = tid; i < 512; i += 256) {
    int n = i >> 2, c = (i & 3) * 8;
    *(uint4*)&Bs[n*40 + c] = *(const uint4*)&Wdt[n*32 + c];
  }
  {
    int r = tid >> 2, c = (tid & 3) * 8;   // 256 chunks exactly
    *(uint4*)&As[r*40 + c] = *(const uint4*)&zg[(size_t)(rbase + r)*LAT + c];
  }
  __syncthreads();
  int w = tid >> 6, l = tid & 63;
  int mrow = w*16, cl = l & 15, jg = l >> 4;
  bf16x8 af = *(const bf16x8*)&As[(mrow + cl)*40 + jg*8];
  #pragma unroll
  for (int nt = 0; nt < 8; ++nt) {
    f32x4 acc = {0.f,0.f,0.f,0.f};
    bf16x8 bf = *(const bf16x8*)&Bs[(nt*16 + cl)*40 + jg*8];
    acc = __builtin_amdgcn_mfma_f32_16x16x32_bf16(af, bf, acc, 0, 0, 0);
    int col = nt*16 + cl;
    float bv = bd[col];
    #pragma unroll
    for (int i = 0; i < 4; ++i) {
      int grow = rbase + mrow + jg*4 + i;
      float v = acc[i] + bv;
      if (grow < NPV) out[(size_t)grow*DMF + col] = v;
      else if (col < DPF) out[OUT_PROV + (size_t)(grow - NPV)*DPF + col] = v;
    }
  }
}

// ---------------- fused passive MLP, MFMA, 64 rows/block ----------------
__global__ __launch_bounds__(256) void k_passm(const float* __restrict__ xm,
                                               const ushort* __restrict__ W1t,
                                               const float* __restrict__ b1,
                                               const ushort* __restrict__ W2t,
                                               const float* __restrict__ b2,
                                               const ushort* __restrict__ Wdt,
                                               const float* __restrict__ bd,
                                               float* __restrict__ out) {
  __shared__ __align__(16) ushort XH[64*136];   // x, overwritten by h (wave-private rows)
  __shared__ __align__(16) ushort ZB[64*40];
  __shared__ __align__(16) ushort B1s[128*136];
  __shared__ __align__(16) ushort B2s[32*136];
  __shared__ __align__(16) ushort Bds[128*40];
  int tid = threadIdx.x;
  int rbase = NPV + blockIdx.x * 64;            // member rows 20000..99999
  for (int i = tid; i < 2048; i += 256) {
    int n = i >> 4, c = (i & 15) * 8;
    *(uint4*)&B1s[n*136 + c] = *(const uint4*)&W1t[n*128 + c];
  }
  for (int i = tid; i < 512; i += 256) {
    int n = i >> 4, c = (i & 15) * 8;
    *(uint4*)&B2s[n*136 + c] = *(const uint4*)&W2t[n*128 + c];
  }
  for (int i = tid; i < 512; i += 256) {
    int n = i >> 2, c = (i & 3) * 8;
    *(uint4*)&Bds[n*40 + c] = *(const uint4*)&Wdt[n*32 + c];
  }
  for (int i = tid; i < 1024; i += 256) {
    int r = i >> 4, c = (i & 15) * 8;
    float4 v0 = *(const float4*)&xm[(size_t)(rbase + r)*DMF + c];
    float4 v1 = *(const float4*)&xm[(size_t)(rbase + r)*DMF + c + 4];
    uint4 u;
    u.x = pack2(v0.x, v0.y); u.y = pack2(v0.z, v0.w);
    u.z = pack2(v1.x, v1.y); u.w = pack2(v1.z, v1.w);
    *(uint4*)&XH[r*136 + c] = u;
  }
  __syncthreads();                              // the ONLY barrier
  int w = tid >> 6, l = tid & 63;
  int mrow = w*16, cl = l & 15, jg = l >> 4;
  // phase 1: h = relu(x@W1 + b1) -> XH in place (rows wave-private; A preloaded)
  {
    bf16x8 af[4];
    #pragma unroll
    for (int s = 0; s < 4; ++s)
      af[s] = *(const bf16x8*)&XH[(mrow + cl)*136 + s*32 + jg*8];
    #pragma unroll
    for (int nt = 0; nt < 8; ++nt) {
      f32x4 acc = {0.f,0.f,0.f,0.f};
      #pragma unroll
      for (int s = 0; s < 4; ++s) {
        bf16x8 bf = *(const bf16x8*)&B1s[(nt*16 + cl)*136 + s*32 + jg*8];
        acc = __builtin_amdgcn_mfma_f32_16x16x32_bf16(af[s], bf, acc, 0, 0, 0);
      }
      int col = nt*16 + cl;
      float bv = b1[col];
      #pragma unroll
      for (int i = 0; i < 4; ++i) {
        float v = acc[i] + bv;
        v = v > 0.f ? v : 0.f;
        XH[(mrow + jg*4 + i)*136 + col] = f2bf(v);
      }
    }
  }
  // phase 2: z = h@W2 + b2 -> ZB
  {
    bf16x8 af[4];
    #pragma unroll
    for (int s = 0; s < 4; ++s)
      af[s] = *(const bf16x8*)&XH[(mrow + cl)*136 + s*32 + jg*8];
    #pragma unroll
    for (int nt = 0; nt < 2; ++nt) {
      f32x4 acc = {0.f,0.f,0.f,0.f};
      #pragma unroll
      for (int s = 0; s < 4; ++s) {
        bf16x8 bf = *(const bf16x8*)&B2s[(nt*16 + cl)*136 + s*32 + jg*8];
        acc = __builtin_amdgcn_mfma_f32_16x16x32_bf16(af[s], bf, acc, 0, 0, 0);
      }
      int col = nt*16 + cl;
      float bv = b2[col];
      #pragma unroll
      for (int i = 0; i < 4; ++i)
        ZB[(mrow + jg*4 + i)*40 + col] = f2bf(acc[i] + bv);
    }
  }
  // phase 3: xhat = z@Wd + bd -> out
  {
    bf16x8 af = *(const bf16x8*)&ZB[(mrow + cl)*40 + jg*8];
    #pragma unroll
    for (int nt = 0; nt < 8; ++nt) {
      f32x4 acc = {0.f,0.f,0.f,0.f};
      bf16x8 bf = *(const bf16x8*)&Bds[(nt*16 + cl)*40 + jg*8];
      acc = __builtin_amdgcn_mfma_f32_16x16x32_bf16(af, bf, acc, 0, 0, 0);
      int col = nt*16 + cl;
      float bv = bd[col];
      #pragma unroll
      for (int i = 0; i < 4; ++i) {
        size_t grow = rbase + mrow + jg*4 + i;
        out[grow*DMF + col] = acc[i] + bv;
      }
    }
  }
}

extern "C" void kernel_launch(void* const* d_in, const int* in_sizes, int n_in,
                              void* d_out, int out_size, void* d_ws, size_t ws_size,
                              hipStream_t stream) {
  const float* xm   = (const float*)d_in[0];
  const float* xp   = (const float*)d_in[1];
  const int*   pidx = (const int*)d_in[2];
  const int*   midx = (const int*)d_in[3];
  const float* W1   = (const float*)d_in[4];
  const float* b1   = (const float*)d_in[5];
  const float* W2   = (const float*)d_in[6];
  const float* b2   = (const float*)d_in[7];
  const float* Wd   = (const float*)d_in[8];
  const float* bd   = (const float*)d_in[9];
  float* out = (float*)d_out;

  // ws layout (bytes):
  // deg[160000] dinv[160000] off[160256] cursor[160000]
  // inc[163840] bsum[160]+pad (to 804480) csr[4000000]
  // W1t[32768] W2t[8192] Wdt[8192]
  // xw1[10240000] h[10240000] xw2[2560000] z[2560000]
  if (ws_size < (size_t)30453632) return;
  char* W = (char*)d_ws;
  int*    deg    = (int*)(W + 0);
  float*  dinv   = (float*)(W + 160000);
  int*    off    = (int*)(W + 320000);
  int*    cursor = (int*)(W + 480256);
  int*    inc    = (int*)(W + 640256);
  int*    bsum   = (int*)(W + 804096);
  int*    csr    = (int*)(W + 804480);
  ushort* W1t    = (ushort*)(W + 4804480);
  ushort* W2t    = (ushort*)(W + 4837248);
  ushort* Wdt    = (ushort*)(W + 4845440);
  ushort* xw1g   = (ushort*)(W + 4853632);
  ushort* hg     = (ushort*)(W + 15093632);
  ushort* xw2g   = (ushort*)(W + 25333632);
  ushort* zg     = (ushort*)(W + 27893632);

  k_prep      <<<1954,  256,  0, stream>>>(W1, W2, Wd, W1t, W2t, Wdt, deg, out);
  k_deg_count <<<1954,  256,  0, stream>>>(pidx, midx, deg);
  k_scan1     <<<40,    1024, 0, stream>>>(deg, dinv, inc, bsum);
  k_scan3     <<<40,    1024, 0, stream>>>(deg, inc, bsum, off, cursor);
  k_fill      <<<1954,  256,  0, stream>>>(pidx, midx, off, cursor, csr);
  k_xw1m      <<<625,   256,  0, stream>>>(xm, xp, W1t, xw1g);
  k_gather1   <<<5000,  256,  0, stream>>>(off, csr, dinv, xw1g, b1, hg);
  k_xw2m      <<<625,   256,  0, stream>>>(hg, W2t, xw2g);
  k_gather2   <<<5000,  256,  0, stream>>>(off, csr, dinv, xw2g, b2, zg);
  k_decm      <<<625,   256,  0, stream>>>(zg, Wdt, bd, out);
  k_passm     <<<1250,  256,  0, stream>>>(xm, W1t, b1, W2t, b2, Wdt, bd, out);
}

// Round 10
// 146.613 us; speedup vs baseline: 5.5645x; 1.1009x over previous
//
#include <hip/hip_runtime.h>

#define NMN 100000
#define NPV 20000
#define DMF 128
#define DPF 64
#define NE  500000
#define HID 128
#define LAT 32
#define NACT (2*NPV)                  // 40000 edge-active nodes
#define OUT_PROV (NMN*DMF)            // 12,800,000
#define OUT_LOG  (OUT_PROV + NPV*DPF) // 14,080,000
#define CAP 128                       // CSR bucket capacity per dst (max deg ~60)

typedef __attribute__((ext_vector_type(8))) short bf16x8;   // 8 bf16 = 4 VGPR
typedef __attribute__((ext_vector_type(4))) float f32x4;    // MFMA C/D

__device__ __forceinline__ ushort f2bf(float f) {
  unsigned u = __float_as_uint(f);
  u = (u + 0x7fffu + ((u >> 16) & 1u)) >> 16;   // RNE
  return (ushort)u;
}
__device__ __forceinline__ float bf2f(ushort h) {
  return __uint_as_float(((unsigned)h) << 16);
}
__device__ __forceinline__ unsigned pack2(float a, float b) {
  return (unsigned)f2bf(a) | ((unsigned)f2bf(b) << 16);
}
__device__ __forceinline__ float lo16(unsigned u) { return bf2f((ushort)(u & 0xffffu)); }
__device__ __forceinline__ float hi16(unsigned u) { return bf2f((ushort)(u >> 16)); }

// ---------------- prep: weight transposes (bf16), zero cursor, zero logits ----------------
__global__ __launch_bounds__(256) void k_prep(const float* __restrict__ W1,
                                              const float* __restrict__ W2,
                                              const float* __restrict__ Wd,
                                              ushort* __restrict__ W1t,
                                              ushort* __restrict__ W2t,
                                              ushort* __restrict__ Wdt,
                                              int* __restrict__ cursor,
                                              float* __restrict__ out) {
  int i = blockIdx.x*256 + threadIdx.x;
  if (i < 16384) {                       // W1t[n*128+k] = W1[k][n]
    int n = i >> 7, k = i & 127;
    W1t[i] = f2bf(W1[k*HID + n]);
  } else if (i < 20480) {                // W2t[n*128+k] = W2[k][n]
    int j = i - 16384;
    int n = j >> 7, k = j & 127;
    W2t[j] = f2bf(W2[k*LAT + n]);
  } else if (i < 24576) {                // Wdt[n*32+k] = Wd[k][n]
    int j = i - 20480;
    int n = j >> 5, k = j & 31;
    Wdt[j] = f2bf(Wd[k*DMF + n]);
  }
  if (i < NACT) cursor[i] = 0;
  if (i < NE) out[OUT_LOG + i] = 0.f;
}

// ---------------- fill bucketed CSR ----------------
__global__ __launch_bounds__(256) void k_fill(const int* __restrict__ pidx,
                                              const int* __restrict__ midx,
                                              int* __restrict__ cursor,
                                              int* __restrict__ csr) {
  int e = blockIdx.x*256 + threadIdx.x;
  if (e >= NE) return;
  int p = pidx[e], m = midx[e];
  int sa = NPV + (m < NPV ? m : NPV - 1);      // clamped provider-side src
  int pos = atomicAdd(&cursor[p], 1);
  if (pos < CAP) csr[p*CAP + pos] = sa;        // edge into member node p
  if (m < NPV) {
    int da = NPV + m;
    int pos2 = atomicAdd(&cursor[da], 1);
    if (pos2 < CAP) csr[da*CAP + pos2] = p;    // edge into provider node da
  }
}

// ---------------- xw1 = x_active @ W1 (unscaled), MFMA, 64 rows/block ----------------
__global__ __launch_bounds__(256) void k_xw1m(const float* __restrict__ xm,
                                              const float* __restrict__ xp,
                                              const ushort* __restrict__ W1t,
                                              ushort* __restrict__ xw1) {
  __shared__ __align__(16) ushort As[64*136];
  __shared__ __align__(16) ushort Bs[128*136];
  int tid = threadIdx.x;
  int rbase = blockIdx.x * 64;
  for (int i = tid; i < 2048; i += 256) {
    int n = i >> 4, c = (i & 15) * 8;
    *(uint4*)&Bs[n*136 + c] = *(const uint4*)&W1t[n*128 + c];
  }
  for (int i = tid; i < 1024; i += 256) {
    int r = i >> 4, c = (i & 15) * 8;
    int a = rbase + r;
    float4 v0 = make_float4(0,0,0,0), v1 = v0;
    if (a < NPV) {
      v0 = *(const float4*)&xm[(size_t)a*DMF + c];
      v1 = *(const float4*)&xm[(size_t)a*DMF + c + 4];
    } else if (c < DPF) {
      int p = a - NPV;
      v0 = *(const float4*)&xp[(size_t)p*DPF + c];
      v1 = *(const float4*)&xp[(size_t)p*DPF + c + 4];
    }
    uint4 u;
    u.x = pack2(v0.x, v0.y); u.y = pack2(v0.z, v0.w);
    u.z = pack2(v1.x, v1.y); u.w = pack2(v1.z, v1.w);
    *(uint4*)&As[r*136 + c] = u;
  }
  __syncthreads();
  int w = tid >> 6, l = tid & 63;
  int mrow = w*16, cl = l & 15, jg = l >> 4;
  bf16x8 af[4];
  #pragma unroll
  for (int s = 0; s < 4; ++s)
    af[s] = *(const bf16x8*)&As[(mrow + cl)*136 + s*32 + jg*8];
  #pragma unroll
  for (int nt = 0; nt < 8; ++nt) {
    f32x4 acc = {0.f,0.f,0.f,0.f};
    #pragma unroll
    for (int s = 0; s < 4; ++s) {
      bf16x8 bf = *(const bf16x8*)&Bs[(nt*16 + cl)*136 + s*32 + jg*8];
      acc = __builtin_amdgcn_mfma_f32_16x16x32_bf16(af[s], bf, acc, 0, 0, 0);
    }
    int col = nt*16 + cl;
    #pragma unroll
    for (int i = 0; i < 4; ++i) {
      int grow = rbase + mrow + jg*4 + i;
      xw1[(size_t)grow*HID + col] = f2bf(acc[i]);
    }
  }
}

__device__ __forceinline__ float rsq_deg(const int* __restrict__ cursor, int node) {
  return rsqrtf((float)(cursor[node] + 1));     // deg = edges + self-loop
}

// ---------------- gather1 + relu + (h @ W2) fused; 2 dsts/wave ----------------
__global__ __launch_bounds__(256) void k_g1f(const int* __restrict__ cursor,
                                             const int* __restrict__ csr,
                                             const ushort* __restrict__ xw1,
                                             const float* __restrict__ b1,
                                             const ushort* __restrict__ W2t,
                                             ushort* __restrict__ xw2) {
  __shared__ unsigned hs[4][2][64];      // per-wave h rows (2 bf16 cols per u32)
  int tid = threadIdx.x;
  int wv = tid >> 6, l = tid & 63;
  int wid = blockIdx.x*4 + wv;           // 5000 blocks * 4 waves = 20000
  int dA = wid*2, dB = wid*2 + 1;
  int cntA = cursor[dA]; if (cntA > CAP) cntA = CAP;
  int cntB = cursor[dB]; if (cntB > CAP) cntB = CAP;
  float ddA = rsqrtf((float)(cntA + 1));
  float ddB = rsqrtf((float)(cntB + 1));
  const unsigned* xb = (const unsigned*)xw1;
  unsigned suA = xb[(size_t)dA*64 + l];
  unsigned suB = xb[(size_t)dB*64 + l];
  float axA = ddA*lo16(suA), ayA = ddA*hi16(suA);
  float axB = ddB*lo16(suB), ayB = ddB*hi16(suB);
  int ia = dA*CAP, aE = ia + cntA;
  int jb = dB*CAP, bE = jb + cntB;
  // dual main loop: 4 edges from each list interleaved -> 8 row-loads in flight
  for (; ia + 4 <= aE && jb + 4 <= bE; ia += 4, jb += 4) {
    int a0 = csr[ia], a1 = csr[ia+1], a2 = csr[ia+2], a3 = csr[ia+3];
    int b0 = csr[jb], b1i = csr[jb+1], b2 = csr[jb+2], b3 = csr[jb+3];
    float dA0 = rsq_deg(cursor,a0), dA1 = rsq_deg(cursor,a1);
    float dA2 = rsq_deg(cursor,a2), dA3 = rsq_deg(cursor,a3);
    float dB0 = rsq_deg(cursor,b0), dB1 = rsq_deg(cursor,b1i);
    float dB2 = rsq_deg(cursor,b2), dB3 = rsq_deg(cursor,b3);
    unsigned uA0 = xb[(size_t)a0*64 + l], uA1 = xb[(size_t)a1*64 + l];
    unsigned uA2 = xb[(size_t)a2*64 + l], uA3 = xb[(size_t)a3*64 + l];
    unsigned uB0 = xb[(size_t)b0*64 + l], uB1 = xb[(size_t)b1i*64 + l];
    unsigned uB2 = xb[(size_t)b2*64 + l], uB3 = xb[(size_t)b3*64 + l];
    axA += dA0*lo16(uA0); ayA += dA0*hi16(uA0);
    axA += dA1*lo16(uA1); ayA += dA1*hi16(uA1);
    axA += dA2*lo16(uA2); ayA += dA2*hi16(uA2);
    axA += dA3*lo16(uA3); ayA += dA3*hi16(uA3);
    axB += dB0*lo16(uB0); ayB += dB0*hi16(uB0);
    axB += dB1*lo16(uB1); ayB += dB1*hi16(uB1);
    axB += dB2*lo16(uB2); ayB += dB2*hi16(uB2);
    axB += dB3*lo16(uB3); ayB += dB3*hi16(uB3);
  }
  for (; ia + 4 <= aE; ia += 4) {
    int a0 = csr[ia], a1 = csr[ia+1], a2 = csr[ia+2], a3 = csr[ia+3];
    float d0 = rsq_deg(cursor,a0), d1 = rsq_deg(cursor,a1);
    float d2 = rsq_deg(cursor,a2), d3 = rsq_deg(cursor,a3);
    unsigned u0 = xb[(size_t)a0*64 + l], u1 = xb[(size_t)a1*64 + l];
    unsigned u2 = xb[(size_t)a2*64 + l], u3 = xb[(size_t)a3*64 + l];
    axA += d0*lo16(u0); ayA += d0*hi16(u0);
    axA += d1*lo16(u1); ayA += d1*hi16(u1);
    axA += d2*lo16(u2); ayA += d2*hi16(u2);
    axA += d3*lo16(u3); ayA += d3*hi16(u3);
  }
  for (; ia < aE; ++ia) {
    int src = csr[ia];
    float ds = rsq_deg(cursor,src);
    unsigned u = xb[(size_t)src*64 + l];
    axA += ds*lo16(u); ayA += ds*hi16(u);
  }
  for (; jb + 4 <= bE; jb += 4) {
    int a0 = csr[jb], a1 = csr[jb+1], a2 = csr[jb+2], a3 = csr[jb+3];
    float d0 = rsq_deg(cursor,a0), d1 = rsq_deg(cursor,a1);
    float d2 = rsq_deg(cursor,a2), d3 = rsq_deg(cursor,a3);
    unsigned u0 = xb[(size_t)a0*64 + l], u1 = xb[(size_t)a1*64 + l];
    unsigned u2 = xb[(size_t)a2*64 + l], u3 = xb[(size_t)a3*64 + l];
    axB += d0*lo16(u0); ayB += d0*hi16(u0);
    axB += d1*lo16(u1); ayB += d1*hi16(u1);
    axB += d2*lo16(u2); ayB += d2*hi16(u2);
    axB += d3*lo16(u3); ayB += d3*hi16(u3);
  }
  for (; jb < bE; ++jb) {
    int src = csr[jb];
    float ds = rsq_deg(cursor,src);
    unsigned u = xb[(size_t)src*64 + l];
    axB += ds*lo16(u); ayB += ds*hi16(u);
  }
  float2 b = ((const float2*)b1)[l];
  float rxA = ddA*axA + b.x; rxA = rxA > 0.f ? rxA : 0.f;
  float ryA = ddA*ayA + b.y; ryA = ryA > 0.f ? ryA : 0.f;
  float rxB = ddB*axB + b.x; rxB = rxB > 0.f ? rxB : 0.f;
  float ryB = ddB*ayB + b.y; ryB = ryB > 0.f ? ryB : 0.f;
  hs[wv][0][l] = pack2(rxA, ryA);        // wave-private LDS; lockstep => no barrier
  hs[wv][1][l] = pack2(rxB, ryB);
  // fused xw2 = h @ W2 : col c per half-lane, partial over 64 k each, combine
  int c = l & 31, half = l >> 5;
  const unsigned* w2 = (const unsigned*)W2t;   // [n][64] u32 (k-pairs)
  float sA = 0.f, sB = 0.f;
  #pragma unroll 8
  for (int j = 0; j < 32; ++j) {
    int jj = half*32 + j;
    unsigned hvA = hs[wv][0][jj];
    unsigned hvB = hs[wv][1][jj];
    unsigned wp  = w2[c*64 + jj];
    float wlo = lo16(wp), whi = hi16(wp);
    sA += lo16(hvA)*wlo; sA += hi16(hvA)*whi;
    sB += lo16(hvB)*wlo; sB += hi16(hvB)*whi;
  }
  sA += __shfl_xor(sA, 32);
  sB += __shfl_xor(sB, 32);
  if (half == 0) xw2[(size_t)dA*LAT + c] = f2bf(sA);
  else           xw2[(size_t)dB*LAT + c] = f2bf(sB);
}

// ---------------- gather2 + (z @ Wdec) fused -> out; 2 dsts/wave ----------------
__global__ __launch_bounds__(256) void k_g2f(const int* __restrict__ cursor,
                                             const int* __restrict__ csr,
                                             const ushort* __restrict__ xw2,
                                             const float* __restrict__ b2,
                                             const ushort* __restrict__ Wdt,
                                             const float* __restrict__ bd,
                                             float* __restrict__ out) {
  __shared__ float zs[4][2][32];
  int tid = threadIdx.x;
  int wv = tid >> 6, l = tid & 63;
  int wid = blockIdx.x*4 + wv;
  int dA = wid*2, dB = wid*2 + 1;
  int cntA = cursor[dA]; if (cntA > CAP) cntA = CAP;
  int cntB = cursor[dB]; if (cntB > CAP) cntB = CAP;
  float ddA = rsqrtf((float)(cntA + 1));
  float ddB = rsqrtf((float)(cntB + 1));
  int half = l >> 5, c = l & 31;
  float accA = 0.f, accB = 0.f;
  int i = dA*CAP + half, aE = dA*CAP + cntA;
  int j = dB*CAP + half, bE = dB*CAP + cntB;
  for (; i + 6 < aE && j + 6 < bE; i += 8, j += 8) {
    int a0 = csr[i], a1 = csr[i+2], a2 = csr[i+4], a3 = csr[i+6];
    int b0 = csr[j], b1i = csr[j+2], b2 = csr[j+4], b3 = csr[j+6];
    float dA0 = rsq_deg(cursor,a0), dA1 = rsq_deg(cursor,a1);
    float dA2 = rsq_deg(cursor,a2), dA3 = rsq_deg(cursor,a3);
    float dB0 = rsq_deg(cursor,b0), dB1 = rsq_deg(cursor,b1i);
    float dB2 = rsq_deg(cursor,b2), dB3 = rsq_deg(cursor,b3);
    float xA0 = bf2f(xw2[(size_t)a0*LAT + c]);
    float xA1 = bf2f(xw2[(size_t)a1*LAT + c]);
    float xA2 = bf2f(xw2[(size_t)a2*LAT + c]);
    float xA3 = bf2f(xw2[(size_t)a3*LAT + c]);
    float xB0 = bf2f(xw2[(size_t)b0*LAT + c]);
    float xB1 = bf2f(xw2[(size_t)b1i*LAT + c]);
    float xB2 = bf2f(xw2[(size_t)b2*LAT + c]);
    float xB3 = bf2f(xw2[(size_t)b3*LAT + c]);
    accA += dA0*xA0; accA += dA1*xA1; accA += dA2*xA2; accA += dA3*xA3;
    accB += dB0*xB0; accB += dB1*xB1; accB += dB2*xB2; accB += dB3*xB3;
  }
  for (; i + 6 < aE; i += 8) {
    int a0 = csr[i], a1 = csr[i+2], a2 = csr[i+4], a3 = csr[i+6];
    float d0 = rsq_deg(cursor,a0), d1 = rsq_deg(cursor,a1);
    float d2 = rsq_deg(cursor,a2), d3 = rsq_deg(cursor,a3);
    float x0 = bf2f(xw2[(size_t)a0*LAT + c]);
    float x1 = bf2f(xw2[(size_t)a1*LAT + c]);
    float x2 = bf2f(xw2[(size_t)a2*LAT + c]);
    float x3 = bf2f(xw2[(size_t)a3*LAT + c]);
    accA += d0*x0; accA += d1*x1; accA += d2*x2; accA += d3*x3;
  }
  for (; i < aE; i += 2) {
    int src = csr[i];
    accA += rsq_deg(cursor,src) * bf2f(xw2[(size_t)src*LAT + c]);
  }
  for (; j + 6 < bE; j += 8) {
    int a0 = csr[j], a1 = csr[j+2], a2 = csr[j+4], a3 = csr[j+6];
    float d0 = rsq_deg(cursor,a0), d1 = rsq_deg(cursor,a1);
    float d2 = rsq_deg(cursor,a2), d3 = rsq_deg(cursor,a3);
    float x0 = bf2f(xw2[(size_t)a0*LAT + c]);
    float x1 = bf2f(xw2[(size_t)a1*LAT + c]);
    float x2 = bf2f(xw2[(size_t)a2*LAT + c]);
    float x3 = bf2f(xw2[(size_t)a3*LAT + c]);
    accB += d0*x0; accB += d1*x1; accB += d2*x2; accB += d3*x3;
  }
  for (; j < bE; j += 2) {
    int src = csr[j];
    accB += rsq_deg(cursor,src) * bf2f(xw2[(size_t)src*LAT + c]);
  }
  accA += __shfl_xor(accA, 32);
  accB += __shfl_xor(accB, 32);
  float resA = ddA*(accA + ddA*bf2f(xw2[(size_t)dA*LAT + c])) + b2[c];
  float resB = ddB*(accB + ddB*bf2f(xw2[(size_t)dB*LAT + c])) + b2[c];
  if (half == 0) {                       // z quantized to bf16 (matches prior pipeline)
    zs[wv][0][c] = bf2f(f2bf(resA));
    zs[wv][1][c] = bf2f(f2bf(resB));
  }
  // fused decode: out[dst][col] = sum_k z[k]*Wd[k][col] + bd[col]; cols l and l+64
  int c0 = l, c1 = l + 64;
  const unsigned* wd32 = (const unsigned*)Wdt;   // [n][16] u32 (k-pairs)
  float oA0 = 0.f, oA1 = 0.f, oB0 = 0.f, oB1 = 0.f;
  #pragma unroll 8
  for (int kk = 0; kk < 16; ++kk) {
    float za0 = zs[wv][0][2*kk], za1 = zs[wv][0][2*kk+1];
    float zb0 = zs[wv][1][2*kk], zb1 = zs[wv][1][2*kk+1];
    unsigned u0 = wd32[c0*16 + kk];
    unsigned u1 = wd32[c1*16 + kk];
    float w00 = lo16(u0), w01 = hi16(u0);
    float w10 = lo16(u1), w11 = hi16(u1);
    oA0 += za0*w00; oA0 += za1*w01;
    oA1 += za0*w10; oA1 += za1*w11;
    oB0 += zb0*w00; oB0 += zb1*w01;
    oB1 += zb0*w10; oB1 += zb1*w11;
  }
  float bd0 = bd[c0], bd1 = bd[c1];
  oA0 += bd0; oA1 += bd1; oB0 += bd0; oB1 += bd1;
  if (dA < NPV) {
    out[(size_t)dA*DMF + c0] = oA0;
    out[(size_t)dA*DMF + c1] = oA1;
    out[(size_t)dB*DMF + c0] = oB0;
    out[(size_t)dB*DMF + c1] = oB1;
  } else {
    if (c0 < DPF) {
      out[OUT_PROV + (size_t)(dA-NPV)*DPF + c0] = oA0;
      out[OUT_PROV + (size_t)(dB-NPV)*DPF + c0] = oB0;
    }
  }
}

// ---------------- fused passive MLP, MFMA, 64 rows/block ----------------
__global__ __launch_bounds__(256) void k_passm(const float* __restrict__ xm,
                                               const ushort* __restrict__ W1t,
                                               const float* __restrict__ b1,
                                               const ushort* __restrict__ W2t,
                                               const float* __restrict__ b2,
                                               const ushort* __restrict__ Wdt,
                                               const float* __restrict__ bd,
                                               float* __restrict__ out) {
  __shared__ __align__(16) ushort XH[64*136];   // x, overwritten by h (wave-private rows)
  __shared__ __align__(16) ushort ZB[64*40];
  __shared__ __align__(16) ushort B1s[128*136];
  __shared__ __align__(16) ushort B2s[32*136];
  __shared__ __align__(16) ushort Bds[128*40];
  int tid = threadIdx.x;
  int rbase = NPV + blockIdx.x * 64;            // member rows 20000..99999
  for (int i = tid; i < 2048; i += 256) {
    int n = i >> 4, c = (i & 15) * 8;
    *(uint4*)&B1s[n*136 + c] = *(const uint4*)&W1t[n*128 + c];
  }
  for (int i = tid; i < 512; i += 256) {
    int n = i >> 4, c = (i & 15) * 8;
    *(uint4*)&B2s[n*136 + c] = *(const uint4*)&W2t[n*128 + c];
  }
  for (int i = tid; i < 512; i += 256) {
    int n = i >> 2, c = (i & 3) * 8;
    *(uint4*)&Bds[n*40 + c] = *(const uint4*)&Wdt[n*32 + c];
  }
  for (int i = tid; i < 1024; i += 256) {
    int r = i >> 4, c = (i & 15) * 8;
    float4 v0 = *(const float4*)&xm[(size_t)(rbase + r)*DMF + c];
    float4 v1 = *(const float4*)&xm[(size_t)(rbase + r)*DMF + c + 4];
    uint4 u;
    u.x = pack2(v0.x, v0.y); u.y = pack2(v0.z, v0.w);
    u.z = pack2(v1.x, v1.y); u.w = pack2(v1.z, v1.w);
    *(uint4*)&XH[r*136 + c] = u;
  }
  __syncthreads();                              // the ONLY barrier
  int w = tid >> 6, l = tid & 63;
  int mrow = w*16, cl = l & 15, jg = l >> 4;
  // phase 1: h = relu(x@W1 + b1) -> XH in place (rows wave-private; A preloaded)
  {
    bf16x8 af[4];
    #pragma unroll
    for (int s = 0; s < 4; ++s)
      af[s] = *(const bf16x8*)&XH[(mrow + cl)*136 + s*32 + jg*8];
    #pragma unroll
    for (int nt = 0; nt < 8; ++nt) {
      f32x4 acc = {0.f,0.f,0.f,0.f};
      #pragma unroll
      for (int s = 0; s < 4; ++s) {
        bf16x8 bf = *(const bf16x8*)&B1s[(nt*16 + cl)*136 + s*32 + jg*8];
        acc = __builtin_amdgcn_mfma_f32_16x16x32_bf16(af[s], bf, acc, 0, 0, 0);
      }
      int col = nt*16 + cl;
      float bv = b1[col];
      #pragma unroll
      for (int i = 0; i < 4; ++i) {
        float v = acc[i] + bv;
        v = v > 0.f ? v : 0.f;
        XH[(mrow + jg*4 + i)*136 + col] = f2bf(v);
      }
    }
  }
  // phase 2: z = h@W2 + b2 -> ZB
  {
    bf16x8 af[4];
    #pragma unroll
    for (int s = 0; s < 4; ++s)
      af[s] = *(const bf16x8*)&XH[(mrow + cl)*136 + s*32 + jg*8];
    #pragma unroll
    for (int nt = 0; nt < 2; ++nt) {
      f32x4 acc = {0.f,0.f,0.f,0.f};
      #pragma unroll
      for (int s = 0; s < 4; ++s) {
        bf16x8 bf = *(const bf16x8*)&B2s[(nt*16 + cl)*136 + s*32 + jg*8];
        acc = __builtin_amdgcn_mfma_f32_16x16x32_bf16(af[s], bf, acc, 0, 0, 0);
      }
      int col = nt*16 + cl;
      float bv = b2[col];
      #pragma unroll
      for (int i = 0; i < 4; ++i)
        ZB[(mrow + jg*4 + i)*40 + col] = f2bf(acc[i] + bv);
    }
  }
  // phase 3: xhat = z@Wd + bd -> out
  {
    bf16x8 af = *(const bf16x8*)&ZB[(mrow + cl)*40 + jg*8];
    #pragma unroll
    for (int nt = 0; nt < 8; ++nt) {
      f32x4 acc = {0.f,0.f,0.f,0.f};
      bf16x8 bf = *(const bf16x8*)&Bds[(nt*16 + cl)*40 + jg*8];
      acc = __builtin_amdgcn_mfma_f32_16x16x32_bf16(af, bf, acc, 0, 0, 0);
      int col = nt*16 + cl;
      float bv = bd[col];
      #pragma unroll
      for (int i = 0; i < 4; ++i) {
        size_t grow = rbase + mrow + jg*4 + i;
        out[grow*DMF + col] = acc[i] + bv;
      }
    }
  }
}

extern "C" void kernel_launch(void* const* d_in, const int* in_sizes, int n_in,
                              void* d_out, int out_size, void* d_ws, size_t ws_size,
                              hipStream_t stream) {
  const float* xm   = (const float*)d_in[0];
  const float* xp   = (const float*)d_in[1];
  const int*   pidx = (const int*)d_in[2];
  const int*   midx = (const int*)d_in[3];
  const float* W1   = (const float*)d_in[4];
  const float* b1   = (const float*)d_in[5];
  const float* W2   = (const float*)d_in[6];
  const float* b2   = (const float*)d_in[7];
  const float* Wd   = (const float*)d_in[8];
  const float* bd   = (const float*)d_in[9];
  float* out = (float*)d_out;

  // ws layout (bytes):
  // cursor[160000] | csr[40000*128*4 = 20480000] | W1t[32768] W2t[8192] Wdt[8192]
  // | xw1[10240000] | xw2[2560000]   => 33,489,152 B
  if (ws_size < (size_t)33489152) return;
  char* W = (char*)d_ws;
  int*    cursor = (int*)(W + 0);
  int*    csr    = (int*)(W + 160000);
  ushort* W1t    = (ushort*)(W + 20640000);
  ushort* W2t    = (ushort*)(W + 20672768);
  ushort* Wdt    = (ushort*)(W + 20680960);
  ushort* xw1g   = (ushort*)(W + 20689152);
  ushort* xw2g   = (ushort*)(W + 30929152);

  k_prep  <<<1954, 256, 0, stream>>>(W1, W2, Wd, W1t, W2t, Wdt, cursor, out);
  k_fill  <<<1954, 256, 0, stream>>>(pidx, midx, cursor, csr);
  k_xw1m  <<<625,  256, 0, stream>>>(xm, xp, W1t, xw1g);
  k_g1f   <<<5000, 256, 0, stream>>>(cursor, csr, xw1g, b1, W2t, xw2g);
  k_g2f   <<<5000, 256, 0, stream>>>(cursor, csr, xw2g, b2, Wdt, bd, out);
  k_passm <<<1250, 256, 0, stream>>>(xm, W1t, b1, W2t, b2, Wdt, bd, out);
}